// Round 11
// baseline (1870.545 us; speedup 1.0000x reference)
//
#include <hip/hip_runtime.h>
#include <hip/hip_bf16.h>
#include <cmath>

typedef __hip_bfloat16 bf16;
typedef __attribute__((ext_vector_type(8))) short short8;
typedef __attribute__((ext_vector_type(4))) short short4_t;
typedef __attribute__((ext_vector_type(4))) float f32x4;
typedef __attribute__((address_space(1))) void as1_void;
typedef __attribute__((address_space(3))) void as3_void;

#define DE   2560
#define HD   512
#define NPAD 30016
#define QNUM 200
#define ADHD 320
#define QR   1600   // 8 heads * 200 q-rows

static __device__ __forceinline__ float bf2f(bf16 v){ return __bfloat162float(v); }
static __device__ __forceinline__ bf16  f2bf(float v){ return __float2bfloat16(v); }
static __device__ __forceinline__ short bfbits(float f){ bf16 b = f2bf(f); return *reinterpret_cast<short*>(&b); }
static __device__ __forceinline__ float geluf(float x){ return 0.5f*x*(1.0f+erff(x*0.70710678118654752440f)); }
static __device__ __forceinline__ float eluf(float x){ return x>0.f ? x : expm1f(x); }

static __device__ __forceinline__ void gload16(const void* g, void* l){
  __builtin_amdgcn_global_load_lds((as1_void*)g, (as3_void*)l, 16, 0, 0);
}

// =================== 256x256 8-phase bf16 NT GEMM (R4-proven loop) ==========
// C[M,N] = act(A[M,K]*B[N,K]^T + bias). BK=64, 512 thr (8 waves 2Mx4N), 128KB
// LDS dbuf. OBF: 1 = bf16 LDS-retiled store, 0 = f32 direct, 2 = f32 atomicAdd.
template<int ACT, int BIAS, int OBF>
__global__ __launch_bounds__(512, 1)
void k_gemm256(const bf16* __restrict__ A, const bf16* __restrict__ B,
               const float* __restrict__ bias, void* __restrict__ Cv,
               int gm, int M, int N, int NB, int K, int lda, int ldb, int ldc,
               long long sA, long long sB, long long sC, int ks)
{
  __shared__ __align__(16) char smem[131072];   // A:[2][32KB] @0, B:[2][32KB] @64KB
  const int bz = blockIdx.z;
  const bf16* Ab = A + (long long)bz * sA;
  const bf16* Bb = B + (long long)bz * sB;
  const long long cbase = (long long)bz * sC;
  int kbeg = 0, kend = K;
  if (ks > 0) { kbeg = bz * ks; kend = kbeg + ks; if (kend > K) kend = K; }

  // block swizzle: XCD-bijective then gm-supertile over M
  const int gx = gridDim.x, gy = gridDim.y;
  const int nwg = gx * gy;
  int orig = blockIdx.y * gx + blockIdx.x;
  {
    const int q8 = nwg >> 3, r8 = nwg & 7;
    const int xcd = orig & 7, idx = orig >> 3;
    orig = (xcd < r8 ? xcd * (q8 + 1) : r8 * (q8 + 1) + (xcd - r8) * q8) + idx;
  }
  const int per_g = gm * gx;
  const int g = orig / per_g, rem = orig - g * per_g;
  int gsz = gy - g * gm; if (gsz > gm) gsz = gm;
  const int mi = g * gm + rem % gsz;
  const int ni = rem / gsz;
  const int m0 = mi * 256, n0 = ni * 256;

  const int tid = threadIdx.x, lane = tid & 63, wave = tid >> 6;
  const int wm = (wave >> 2) * 128, wn = (wave & 3) * 64;
  const int fr = lane & 15, fg = lane >> 4;
  const int cS0 = ((fg) ^ (fr & 7)) * 16;
  const int cS1 = ((4 + fg) ^ (fr & 7)) * 16;

  const bf16* pA[2][2]; const bf16* pB[2][2];
  #pragma unroll
  for (int L = 0; L < 2; L++) {
    const int ch = L * 512 + tid;
    const int lr = ch >> 3;
    #pragma unroll
    for (int mh = 0; mh < 2; mh++) {
      int r = (lr & 63) + mh * 64 + ((lr & 64) << 1);
      int cs = (ch & 7) ^ (r & 7);
      int gr = m0 + r; if (gr > M - 1) gr = M - 1;
      pA[mh][L] = Ab + (long long)gr * lda + cs * 8;
    }
    #pragma unroll
    for (int nh = 0; nh < 2; nh++) {
      int r = nh * 32 + (lr & 31) + ((lr >> 5) << 6);
      int cs = (ch & 7) ^ (r & 7);
      int gr = n0 + r; if (gr > NB - 1) gr = NB - 1;
      pB[nh][L] = Bb + (long long)gr * ldb + cs * 8;
    }
  }

  #define STG_A(mh, buf, kk) do {                                        \
    char* d_ = smem + (buf) * 32768 + ((mh) * 64 + wave * 8) * 128;      \
    gload16(pA[mh][0] + (kk), d_);                                       \
    gload16(pA[mh][1] + (kk), d_ + 16384);                               \
  } while (0)
  #define STG_B(nh, buf, kk) do {                                        \
    char* d_ = smem + 65536 + (buf) * 32768 +                            \
               ((nh) * 32 + (wave & 3) * 8 + (wave >> 2) * 64) * 128;    \
    gload16(pB[nh][0] + (kk), d_);                                       \
    gload16(pB[nh][1] + (kk), d_ + 16384);                               \
  } while (0)

  f32x4 acc[8][4];
  #pragma unroll
  for (int i = 0; i < 8; i++)
    #pragma unroll
    for (int j = 0; j < 4; j++) acc[i][j] = (f32x4){0.f, 0.f, 0.f, 0.f};

  const int nt = (kend - kbeg) / 64;
  // prologue: tile 0 -> buf 0, granule NEED-order A0,B0,B1,A1
  STG_A(0, 0, kbeg); STG_B(0, 0, kbeg); STG_B(1, 0, kbeg); STG_A(1, 0, kbeg);

  #define LOAD_A(mh) do {                                                \
    _Pragma("unroll")                                                    \
    for (int i = 0; i < 4; i++) {                                        \
      const char* p_ = Ab_l + (wm + (mh) * 64 + i * 16 + fr) * 128;      \
      a_[i][0] = *(const short8*)(p_ + cS0);                             \
      a_[i][1] = *(const short8*)(p_ + cS1);                             \
    }                                                                    \
  } while (0)
  #define LOAD_B(nh) do {                                                \
    _Pragma("unroll")                                                    \
    for (int j = 0; j < 2; j++) {                                        \
      const char* p_ = Bb_l + (wn + (nh) * 32 + j * 16 + fr) * 128;      \
      b_[j][0] = *(const short8*)(p_ + cS0);                             \
      b_[j][1] = *(const short8*)(p_ + cS1);                             \
    }                                                                    \
  } while (0)
  #define MFMA_Q(mh, nh) do {                                            \
    __builtin_amdgcn_s_setprio(1);                                       \
    _Pragma("unroll")                                                    \
    for (int i = 0; i < 4; i++)                                          \
      _Pragma("unroll")                                                  \
      for (int j = 0; j < 2; j++) {                                      \
        acc[(mh)*4+i][(nh)*2+j] = __builtin_amdgcn_mfma_f32_16x16x32_bf16( \
            a_[i][0], b_[j][0], acc[(mh)*4+i][(nh)*2+j], 0, 0, 0);       \
        acc[(mh)*4+i][(nh)*2+j] = __builtin_amdgcn_mfma_f32_16x16x32_bf16( \
            a_[i][1], b_[j][1], acc[(mh)*4+i][(nh)*2+j], 0, 0, 0);       \
      }                                                                  \
    __builtin_amdgcn_s_setprio(0);                                       \
  } while (0)

  for (int t = 0; t < nt; t++) {
    const int buf = t & 1, nb = buf ^ 1;
    const int kn = kbeg + (t + 1) * 64;
    const bool pf = (t + 1 < nt);
    const char* Ab_l = smem + buf * 32768;
    const char* Bb_l = smem + 65536 + buf * 32768;
    short8 a_[4][2], b_[2][2];

    asm volatile("s_waitcnt vmcnt(4)" ::: "memory");
    __builtin_amdgcn_s_barrier();
    LOAD_A(0); LOAD_B(0);
    if (pf) STG_A(0, nb, kn);
    MFMA_Q(0, 0);

    if (pf) { asm volatile("s_waitcnt vmcnt(4)" ::: "memory"); }
    else    { asm volatile("s_waitcnt vmcnt(2)" ::: "memory"); }
    __builtin_amdgcn_s_barrier();
    LOAD_B(1);
    if (pf) STG_B(0, nb, kn);
    MFMA_Q(0, 1);

    if (pf) { asm volatile("s_waitcnt vmcnt(4)" ::: "memory"); }
    else    { asm volatile("s_waitcnt vmcnt(0)" ::: "memory"); }
    __builtin_amdgcn_s_barrier();
    LOAD_A(1);
    if (pf) STG_B(1, nb, kn);
    MFMA_Q(1, 1);

    __builtin_amdgcn_s_barrier();
    LOAD_B(0);
    if (pf) STG_A(1, nb, kn);
    MFMA_Q(1, 0);
  }
  #undef LOAD_A
  #undef LOAD_B
  #undef MFMA_Q
  #undef STG_A
  #undef STG_B

  // ---- epilogue ----
  asm volatile("s_waitcnt vmcnt(0)" ::: "memory");
  __builtin_amdgcn_s_barrier();
  float bv_[4];
  #pragma unroll
  for (int j = 0; j < 4; j++) {
    int c = n0 + wn + j * 16 + fr;
    bv_[j] = (BIAS && c < N) ? bias[c] : 0.f;
  }

  if (OBF == 0 || OBF == 2) {
    float* Cf = (float*)Cv;
    #pragma unroll
    for (int i = 0; i < 8; i++)
      #pragma unroll
      for (int j = 0; j < 4; j++) {
        const int col = n0 + wn + j * 16 + fr;
        if (col >= N) continue;
        #pragma unroll
        for (int r = 0; r < 4; r++) {
          const int row = m0 + wm + i * 16 + fg * 4 + r;
          if (row >= M) continue;
          float v = acc[i][j][r];
          if (BIAS) v += bv_[j];
          if (OBF == 2) atomicAdd(&Cf[cbase + (long long)row * ldc + col], v);
          else          Cf[cbase + (long long)row * ldc + col] = v;
        }
      }
  } else {
    bf16* Cb = (bf16*)Cv;
    bf16* epi = (bf16*)(smem + wave * 16384);   // [128 rows][64 cols]
    #pragma unroll
    for (int i = 0; i < 8; i++)
      #pragma unroll
      for (int j = 0; j < 4; j++)
        #pragma unroll
        for (int r = 0; r < 4; r++) {
          float v = acc[i][j][r];
          if (BIAS) v += bv_[j];
          if (ACT == 1) v = geluf(v);
          else if (ACT == 2) v = eluf(v);
          epi[(i * 16 + fg * 4 + r) * 64 + j * 16 + fr] = f2bf(v);
        }
    #pragma unroll
    for (int it = 0; it < 16; it++) {
      int lrow = it * 8 + (lane >> 3);
      int grow = m0 + wm + lrow;
      int gcol = n0 + wn + (lane & 7) * 8;
      if (grow < M && gcol < N)
        *(short8*)(Cb + cbase + (long long)grow * ldc + gcol) =
            *(const short8*)(epi + lrow * 64 + (lane & 7) * 8);
    }
  }
}

// ---------------- 128-tile NT GEMM (small-M / batched / split-K) ----------------
template<int ACT, int BIAS, int OBF, int TROUT>
__global__ __launch_bounds__(256)
void k_gemm_nt(const bf16* __restrict__ A, const bf16* __restrict__ B,
               const float* __restrict__ bias, void* __restrict__ Cv,
               int M, int N, int K, int lda, int ldb, int ldc,
               long long sA, long long sB, long long sC, int nsplit, int ks)
{
  __shared__ __align__(16) bf16 As[3][128*32];
  __shared__ __align__(16) bf16 Bs[3][128*32];
  const int zb = blockIdx.z;
  const int b  = zb / nsplit;
  const int sl = zb - b*nsplit;
  const int kbeg = sl * ks;
  int kend = kbeg + ks; if (kend > K) kend = K;
  const int nt = (kend > kbeg) ? (kend - kbeg + 31) / 32 : 0;

  const bf16* Ab = A + (long long)b * sA;
  const bf16* Bb = B + (long long)b * sB;
  const long long cbase = (long long)b * sC;

  const int NTt = gridDim.x, MTt = gridDim.y;
  const int nwg = NTt * MTt;
  int orig = blockIdx.y * NTt + blockIdx.x;
  {
    const int q8 = nwg >> 3, r8 = nwg & 7;
    const int xcd = orig & 7, idx = orig >> 3;
    orig = (xcd < r8 ? xcd * (q8 + 1) : r8 * (q8 + 1) + (xcd - r8) * q8) + idx;
  }
  const int GM = 8;
  const int per_g = GM * NTt;
  const int g = orig / per_g, rem = orig - g * per_g;
  int gsz = MTt - g * GM; if (gsz > GM) gsz = GM;
  const int mi = g * GM + rem % gsz;
  const int ni = rem / gsz;

  const int m0 = mi * 128, n0 = ni * 128;
  const int tid = threadIdx.x, lane = tid & 63, wave = tid >> 6;
  const int wm = (wave >> 1) * 64, wn = (wave & 1) * 64;
  const int fr = lane & 15, fg = lane >> 4;
  const int fgs = fg ^ ((fr >> 1) & 3);

  f32x4 acc[4][4];
  #pragma unroll
  for (int i = 0; i < 4; i++)
    #pragma unroll
    for (int j = 0; j < 4; j++) acc[i][j] = (f32x4){0.f, 0.f, 0.f, 0.f};

  const int c0 = wave * 128 + lane;
  const int c1 = c0 + 64;
  const int rA0 = c0 >> 2, rA1 = c1 >> 2;
  const int cc0 = ((c0 & 3) ^ ((rA0 >> 1) & 3)) * 8;
  const int cc1 = ((c1 & 3) ^ ((rA1 >> 1) & 3)) * 8;
  int gra0 = m0 + rA0; if (gra0 >= M) gra0 = M - 1;
  int gra1 = m0 + rA1; if (gra1 >= M) gra1 = M - 1;
  int grb0 = n0 + rA0; if (grb0 >= N) grb0 = N - 1;
  int grb1 = n0 + rA1; if (grb1 >= N) grb1 = N - 1;
  const bf16* pa0 = Ab + (long long)gra0 * lda + cc0;
  const bf16* pa1 = Ab + (long long)gra1 * lda + cc1;
  const bf16* pb0 = Bb + (long long)grb0 * ldb + cc0;
  const bf16* pb1 = Bb + (long long)grb1 * ldb + cc1;

  char* lA = (char*)&As[0][0] + wave * 2048;
  char* lB = (char*)&Bs[0][0] + wave * 2048;

  #define STAGE(buf, kk) do {                       \
    char* a_ = lA + (buf) * 8192;                   \
    char* b_ = lB + (buf) * 8192;                   \
    gload16(pa0 + (kk), a_);                        \
    gload16(pa1 + (kk), a_ + 1024);                 \
    gload16(pb0 + (kk), b_);                        \
    gload16(pb1 + (kk), b_ + 1024);                 \
  } while (0)

  if (nt > 0) STAGE(0, kbeg);
  if (nt > 1) STAGE(1, kbeg + 32);

  int cur = 0;
  for (int t = 0; t < nt; t++) {
    if (t + 2 < nt) {
      int n2 = cur + 2; if (n2 >= 3) n2 -= 3;
      STAGE(n2, kbeg + (t + 2) * 32);
      asm volatile("s_waitcnt vmcnt(8)" ::: "memory");
    } else if (t + 1 < nt) {
      asm volatile("s_waitcnt vmcnt(4)" ::: "memory");
    } else {
      asm volatile("s_waitcnt vmcnt(0)" ::: "memory");
    }
    __builtin_amdgcn_s_barrier();

    const bf16* Asb = (const bf16*)((const char*)&As[0][0] + cur * 8192);
    const bf16* Bsb = (const bf16*)((const char*)&Bs[0][0] + cur * 8192);
    short8 af[4], bfv[4];
    #pragma unroll
    for (int i = 0; i < 4; i++) {
      af[i]  = *(const short8*)(Asb + (wm + i * 16 + fr) * 32 + fgs * 8);
      bfv[i] = *(const short8*)(Bsb + (wn + i * 16 + fr) * 32 + fgs * 8);
    }
    #pragma unroll
    for (int i = 0; i < 4; i++)
      #pragma unroll
      for (int j = 0; j < 4; j++)
        acc[i][j] = __builtin_amdgcn_mfma_f32_16x16x32_bf16(af[i], bfv[j], acc[i][j], 0, 0, 0);

    asm volatile("s_waitcnt lgkmcnt(0)" ::: "memory");
    __builtin_amdgcn_s_barrier();
    cur = cur + 1; if (cur >= 3) cur = 0;
  }
  #undef STAGE

  #pragma unroll
  for (int i = 0; i < 4; i++) {
    const int r0 = m0 + wm + i * 16 + fg * 4;
    #pragma unroll
    for (int j = 0; j < 4; j++) {
      const int col = n0 + wn + j * 16 + fr;
      if (col >= N) continue;
      float bv = 0.f;
      if (BIAS) bv = bias[col];
      #pragma unroll
      for (int r = 0; r < 4; r++) {
        const int row = r0 + r;
        if (row >= M) continue;
        float v = acc[i][j][r] + bv;
        if (ACT == 1) v = geluf(v);
        else if (ACT == 2) v = eluf(v);
        long long off;
        if (TROUT) off = cbase + (long long)col * ldc + row;
        else       off = cbase + (long long)row * ldc + col;
        if (OBF == 1)      ((bf16*)Cv)[off] = f2bf(v);
        else if (OBF == 2) atomicAdd(&((float*)Cv)[off], v);
        else               ((float*)Cv)[off] = v;
      }
    }
  }
}

// ---------------- small utility kernels ----------------
__global__ void k_zero(float* p, long long n) {
  long long i = (long long)blockIdx.x * blockDim.x + threadIdx.x;
  long long st = (long long)gridDim.x * blockDim.x;
  for (; i < n; i += st) p[i] = 0.f;
}

__global__ void k_zero_u32(unsigned* p, int n) {
  int i = blockIdx.x * 256 + threadIdx.x;
  if (i < n) p[i] = 0u;
}

__global__ void k_f2bf(const float* __restrict__ in, bf16* __restrict__ out, long long n) {
  long long i = (long long)blockIdx.x * 256 + threadIdx.x;
  if (i < n) out[i] = f2bf(in[i]);
}

__global__ void k_add_emb(const float* __restrict__ x, const float* __restrict__ ns,
                          bf16* __restrict__ h0, long long n4) {
  long long i = (long long)blockIdx.x * 256 + threadIdx.x;
  long long st = (long long)gridDim.x * 256;
  for (; i < n4; i += st) {
    float4 v = ((const float4*)x)[i];
    int d = (int)(i % (DE / 4)) * 4;
    short4_t o;
    o.x = bfbits(v.x + ns[d]);
    o.y = bfbits(v.y + ns[d + 1]);
    o.z = bfbits(v.z + ns[d + 2]);
    o.w = bfbits(v.w + ns[d + 3]);
    ((short4_t*)h0)[i] = o;
  }
}

// transpose f32 [R,C] -> bf16 [C,R]; R,C multiples of 32
__global__ void k_transpose_bf(const float* __restrict__ W, bf16* __restrict__ Wt, int R, int C) {
  __shared__ float t[32][33];
  int c0 = blockIdx.x * 32, r0 = blockIdx.y * 32;
  int x = threadIdx.x, y = threadIdx.y;
  #pragma unroll
  for (int j = 0; j < 32; j += 8)
    t[y + j][x] = W[(long long)(r0 + y + j) * C + c0 + x];
  __syncthreads();
  #pragma unroll
  for (int j = 0; j < 32; j += 8)
    Wt[(long long)(c0 + y + j) * R + r0 + x] = f2bf(t[x][y + j]);
}

// transpose bf16 src[Nv][DE] -> dst[DE][NPAD], zero-fill rows >= Nv
__global__ void k_transpose_h(const bf16* __restrict__ src, bf16* __restrict__ dst, int Nv) {
  __shared__ bf16 t[32][34];
  int n0 = blockIdx.x * 32, d0 = blockIdx.y * 32;
  int x = threadIdx.x, y = threadIdx.y;
  #pragma unroll
  for (int j = 0; j < 32; j += 8) {
    int n = n0 + y + j;
    t[y + j][x] = (n < Nv) ? src[(long long)n * DE + d0 + x] : f2bf(0.f);
  }
  __syncthreads();
  #pragma unroll
  for (int j = 0; j < 32; j += 8)
    dst[(long long)(d0 + y + j) * NPAD + n0 + x] = t[x][y + j];
}

// ---- CSR build (dst-indexed) ----
__global__ void k_count_dst(const int* __restrict__ ei, int E, int TOT, unsigned* __restrict__ cnt) {
  int e = blockIdx.x * 256 + threadIdx.x;
  if (e >= TOT) return;
  int d = (e < E) ? ei[E + e] : (e - E);
  atomicAdd(&cnt[d], 1u);
}

__global__ __launch_bounds__(1024)
void k_scan(const unsigned* __restrict__ cnt, int n, int* __restrict__ rowptr) {
  __shared__ unsigned tot[1024];
  int t = threadIdx.x;
  int ch = (n + 1023) / 1024;
  int beg = t * ch, end = beg + ch; if (end > n) end = n; if (beg > n) beg = n;
  unsigned s = 0;
  for (int i = beg; i < end; i++) s += cnt[i];
  tot[t] = s;
  __syncthreads();
  for (int o = 1; o < 1024; o <<= 1) {
    unsigned u = (t >= o) ? tot[t - o] : 0u;
    __syncthreads();
    tot[t] += u;
    __syncthreads();
  }
  unsigned run = tot[t] - s;
  for (int i = beg; i < end; i++) { rowptr[i] = (int)run; run += cnt[i]; }
  if (t == 1023) rowptr[n] = (int)tot[1023];
}

__global__ void k_scatter(const int* __restrict__ ei, int E, int TOT,
                          const int* __restrict__ rowptr, unsigned* __restrict__ cursor,
                          int* __restrict__ esrc) {
  int e = blockIdx.x * 256 + threadIdx.x;
  if (e >= TOT) return;
  int s, d;
  if (e < E) { s = ei[e]; d = ei[E + e]; } else { s = d = e - E; }
  unsigned pos = atomicAdd(&cursor[d], 1u);
  esrc[rowptr[d] + pos] = s;
}

// es/ed per node: block = 512 threads, wave w = head
__global__ __launch_bounds__(512)
void k_esed(const bf16* __restrict__ hh, const float* __restrict__ asrc,
            const float* __restrict__ adst, float* __restrict__ es, float* __restrict__ ed) {
  int n = blockIdx.x;
  int h = threadIdx.x >> 6;
  int c = threadIdx.x & 63;
  float v = bf2f(hh[(long long)n * HD + h * 64 + c]);
  float s = v * asrc[h * 64 + c];
  float d = v * adst[h * 64 + c];
  #pragma unroll
  for (int o = 32; o; o >>= 1) { s += __shfl_down(s, o, 64); d += __shfl_down(d, o, 64); }
  if (c == 0) { es[n * 8 + h] = s; ed[n * 8 + h] = d; }
}

// fused GAT aggregation: one wave per destination node; 2-edge unrolled gather.
template<int ACT>
__global__ __launch_bounds__(256)
void k_gat_aggr(const int* __restrict__ rowptr, const int* __restrict__ esrc,
                const bf16* __restrict__ hh, const float* __restrict__ es,
                const float* __restrict__ ed, const float* __restrict__ gb,
                bf16* __restrict__ outp, int Nn)
{
  int w = blockIdx.x * 4 + (threadIdx.x >> 6);
  if (w >= Nn) return;
  int lane = threadIdx.x & 63;
  int h = lane >> 3;
  int beg = rowptr[w], end = rowptr[w + 1];
  float edh = ed[w * 8 + h];
  float mx = -3.0e38f;
  for (int e = beg; e < end; e++) {
    int s = esrc[e];
    float l = es[s * 8 + h] + edh;
    l = l > 0.f ? l : 0.2f * l;
    mx = fmaxf(mx, l);
  }
  float den = 0.f;
  float acc[8] = {0.f, 0.f, 0.f, 0.f, 0.f, 0.f, 0.f, 0.f};
  int e = beg;
  for (; e + 1 < end; e += 2) {
    int s0 = esrc[e], s1 = esrc[e + 1];
    float l0 = es[s0 * 8 + h] + edh; l0 = l0 > 0.f ? l0 : 0.2f * l0;
    float l1 = es[s1 * 8 + h] + edh; l1 = l1 > 0.f ? l1 : 0.2f * l1;
    float ex0 = expf(l0 - mx), ex1 = expf(l1 - mx);
    den += ex0 + ex1;
    short8 v0 = *(const short8*)(hh + (long long)s0 * HD + lane * 8);
    short8 v1 = *(const short8*)(hh + (long long)s1 * HD + lane * 8);
    #pragma unroll
    for (int j = 0; j < 8; j++) {
      short a0 = v0[j], a1 = v1[j];
      acc[j] += ex0 * bf2f(*reinterpret_cast<bf16*>(&a0))
              + ex1 * bf2f(*reinterpret_cast<bf16*>(&a1));
    }
  }
  if (e < end) {
    int s = esrc[e];
    float l = es[s * 8 + h] + edh; l = l > 0.f ? l : 0.2f * l;
    float ex = expf(l - mx);
    den += ex;
    short8 v = *(const short8*)(hh + (long long)s * HD + lane * 8);
    #pragma unroll
    for (int j = 0; j < 8; j++) {
      short a = v[j];
      acc[j] += ex * bf2f(*reinterpret_cast<bf16*>(&a));
    }
  }
  float rs = 1.f / (den + 1e-16f);
  short8 o;
  #pragma unroll
  for (int j = 0; j < 8; j++) {
    float val = acc[j] * rs + gb[lane * 8 + j];
    if (ACT == 2) val = eluf(val);
    o[j] = bfbits(val);
  }
  *(short8*)(outp + (long long)w * HD + lane * 8) = o;
}

template<int ACT, int BIAS, int TOBF>
__global__ void k_postproc(float* __restrict__ acc, const float* __restrict__ bias,
                           bf16* __restrict__ obf, long long tot, int cols) {
  long long i = (long long)blockIdx.x * 256 + threadIdx.x;
  if (i >= tot) return;
  int c = (int)(i % cols);
  float v = acc[i];
  if (BIAS) v += bias[c];
  if (ACT == 1) v = geluf(v);
  if (TOBF) obf[i] = f2bf(v);
  else acc[i] = v;
}

// row softmax (in-place), LDS-cached row: scores bf16 [rows][NPAD], scale folded
__global__ __launch_bounds__(256)
void k_softmax_row(bf16* s_all, int NV) {
  __shared__ __align__(16) bf16 srow[NPAD];   // 60 KB -> 2 blocks/CU
  __shared__ float red[4];
  long long row = blockIdx.x;
  bf16* s = s_all + row * NPAD;
  int tid = threadIdx.x;
  for (int c = tid * 8; c < NV; c += 2048)
    *(short8*)(srow + c) = *(const short8*)(s + c);
  __syncthreads();
  float mx = -3.0e38f;
  for (int c = tid; c < NV; c += 256) mx = fmaxf(mx, bf2f(srow[c]));
  #pragma unroll
  for (int o = 32; o; o >>= 1) mx = fmaxf(mx, __shfl_down(mx, o, 64));
  if ((tid & 63) == 0) red[tid >> 6] = mx;
  __syncthreads();
  mx = fmaxf(fmaxf(red[0], red[1]), fmaxf(red[2], red[3]));
  const float inv = 0.05590169943749474f;  // 1/sqrt(320)
  float sm = 0.f;
  for (int c = tid; c < NV; c += 256) sm += expf((bf2f(srow[c]) - mx) * inv);
  #pragma unroll
  for (int o = 32; o; o >>= 1) sm += __shfl_down(sm, o, 64);
  __syncthreads();
  if ((tid & 63) == 0) red[tid >> 6] = sm;
  __syncthreads();
  sm = red[0] + red[1] + red[2] + red[3];
  float rs = 1.f / sm;
  for (int c = tid * 8; c < NPAD; c += 2048) {
    short8 o;
    #pragma unroll
    for (int j = 0; j < 8; j++) {
      int cc = c + j;
      float v = (cc < NV) ? expf((bf2f(srow[cc]) - mx) * inv) * rs : 0.f;
      o[j] = bfbits(v);
    }
    *(short8*)(s + c) = o;
  }
}

// LayerNorm(a+b) row of DE, optional bf16 dup
template<int WB>
__global__ __launch_bounds__(256)
void k_ln(const float* __restrict__ a, const float* __restrict__ b,
          const float* __restrict__ g, const float* __restrict__ bt,
          float* __restrict__ out, bf16* __restrict__ obf) {
  long long row = blockIdx.x;
  __shared__ float xs[DE];
  __shared__ float red[4];
  int tid = threadIdx.x;
  float sum = 0.f;
  for (int c = tid; c < DE; c += 256) {
    float v = a[row * DE + c] + b[row * DE + c];
    xs[c] = v; sum += v;
  }
  #pragma unroll
  for (int o = 32; o; o >>= 1) sum += __shfl_down(sum, o, 64);
  if ((tid & 63) == 0) red[tid >> 6] = sum;
  __syncthreads();
  float mean = (red[0] + red[1] + red[2] + red[3]) * (1.f / DE);
  float vs = 0.f;
  for (int c = tid; c < DE; c += 256) { float t = xs[c] - mean; vs += t * t; }
  #pragma unroll
  for (int o = 32; o; o >>= 1) vs += __shfl_down(vs, o, 64);
  __syncthreads();
  if ((tid & 63) == 0) red[tid >> 6] = vs;
  __syncthreads();
  float var = (red[0] + red[1] + red[2] + red[3]) * (1.f / DE);
  float sc = rsqrtf(var + 1e-5f);
  for (int c = tid; c < DE; c += 256) {
    float v = (xs[c] - mean) * sc * g[c] + bt[c];
    out[row * DE + c] = v;
    if (WB) obf[row * DE + c] = f2bf(v);
  }
}

// ---------------- host ----------------
extern "C" void kernel_launch(void* const* d_in, const int* in_sizes, int n_in,
                              void* d_out, int out_size, void* d_ws, size_t ws_size,
                              hipStream_t stream)
{
  const float* x       = (const float*)d_in[0];
  const int*   ei      = (const int*)d_in[1];
  const float* ns_emb  = (const float*)d_in[2];
  const float* gat_w0  = (const float*)d_in[3];
  const float* gat_wr  = (const float*)d_in[4];
  const float* a_src   = (const float*)d_in[5];
  const float* a_dst   = (const float*)d_in[6];
  const float* gat_b   = (const float*)d_in[7];
  const float* proj_w1 = (const float*)d_in[8];
  const float* proj_b1 = (const float*)d_in[9];
  const float* proj_w2 = (const float*)d_in[10];
  const float* proj_b2 = (const float*)d_in[11];
  const float* queries = (const float*)d_in[12];
  const float* wq = (const float*)d_in[13]; const float* bq = (const float*)d_in[14];
  const float* wk = (const float*)d_in[15];
  const float* wv = (const float*)d_in[17]; const float* bv = (const float*)d_in[18];
  const float* wo = (const float*)d_in[19]; const float* bo = (const float*)d_in[20];
  const float* ln1g = (const float*)d_in[21]; const float* ln1b = (const float*)d_in[22];
  const float* fw1 = (const float*)d_in[23]; const float* fb1 = (const float*)d_in[24];
  const float* fw2 = (const float*)d_in[25]; const float* fb2 = (const float*)d_in[26];
  const float* ln2g = (const float*)d_in[27]; const float* ln2b = (const float*)d_in[28];
  float* out = (float*)d_out;

  const int N = in_sizes[0] / DE;   // 30000
  const int E = in_sizes[1] / 2;    // 90000
  const int TOT = E + N;            // 120000
  const int MT2 = (N + 255) / 256;  // 118

  char* base = (char*)d_ws;
  size_t off = 0;
  auto AL = [&](size_t bytes) -> void* {
    void* p = base + off;
    off += (bytes + 255) & ~(size_t)255;
    return p;
  };
  bf16* wt_g0 = (bf16*)AL((size_t)HD * DE * 2);
  bf16* wt_g1 = (bf16*)AL((size_t)HD * HD * 2);
  bf16* wt_g2 = (bf16*)AL((size_t)HD * HD * 2);
  bf16* wt_p1 = (bf16*)AL((size_t)HD * HD * 2);
  bf16* wt_p2 = (bf16*)AL((size_t)DE * HD * 2);
  bf16* wt_q  = (bf16*)AL((size_t)DE * DE * 2);
  bf16* wkb   = (bf16*)AL((size_t)DE * DE * 2);   // Wk untransposed, bf16
  bf16* wt_v  = (bf16*)AL((size_t)DE * DE * 2);   // Wv^T
  bf16* wt_o  = (bf16*)AL((size_t)DE * DE * 2);
  bf16* wt_f1 = (bf16*)AL((size_t)4 * DE * DE * 2);
  bf16* wt_f2 = (bf16*)AL((size_t)4 * DE * DE * 2);
  bf16* big0  = (bf16*)AL((size_t)N * DE * 2);      // h0 -> hD
  // bigX carve: QK_bf (8.2MB) + T_f (16.4MB) + T_bf (8.2MB) within 153.6MB
  char* bigX  = (char*)AL((size_t)N * DE * 2);
  bf16*  QK_bf = (bf16*)bigX;
  float* T_f   = (float*)(bigX + (size_t)QR * DE * 2);
  bf16*  T_bf  = (bf16*)((char*)T_f + (size_t)QR * DE * 4);
  bf16* hDT   = (bf16*)AL((size_t)DE * NPAD * 2);   // hD transposed, pad rows zeroed
  // GAT scratch block; union'd with scores buffer `sc` (used after GAT dies)
  const size_t scBytes = (size_t)QR * NPAD * 2;     // 96.05 MB
  size_t gatBytes = 2 * (size_t)N * HD * 2 + 2 * (size_t)N * 8 * 4
                  + (size_t)(N + 1) * 4 + (size_t)TOT * 4 + (size_t)N * 4 + 4096;
  char* gat_blk = (char*)AL(gatBytes > scBytes ? gatBytes : scBytes);
  bf16* hhA = (bf16*)gat_blk;
  bf16* hB  = hhA + (size_t)N * HD;
  float* es  = (float*)(hB + (size_t)N * HD);
  float* edv = es + (size_t)N * 8;
  int* rowptr = (int*)(edv + (size_t)N * 8);
  int* esrc   = rowptr + (N + 1);
  unsigned* cnt = (unsigned*)(esrc + TOT);
  bf16* sc = (bf16*)gat_blk;  // scores/attn [QR][NPAD]
  // small f32 pool (zeroed once; targets of split-K atomic GEMMs)
  float* q_f     = (float*)AL((size_t)QNUM * DE * 4);
  float* ctx_f   = (float*)AL((size_t)QNUM * DE * 4);
  float* attnout = (float*)AL((size_t)QNUM * DE * 4);
  float* f1_f    = (float*)AL((size_t)QNUM * 4 * DE * 4);
  float* f2_f    = (float*)AL((size_t)QNUM * DE * 4);
  bf16* qs_bf  = (bf16*)AL((size_t)QNUM * DE * 2);
  bf16* q_bf   = (bf16*)AL((size_t)QNUM * DE * 2);
  bf16* ctx_bf = (bf16*)AL((size_t)QNUM * DE * 2);
  float* attended = (float*)AL((size_t)QNUM * DE * 4);
  bf16* att_bf = (bf16*)AL((size_t)QNUM * DE * 2);
  bf16* f1_bf  = (bf16*)AL((size_t)QNUM * 4 * DE * 2);

  dim3 blk(256);
  dim3 tblk(32, 8);

  // weight prep
  k_transpose_bf<<<dim3(HD / 32, DE / 32), tblk, 0, stream>>>(gat_w0, wt_g0, DE, HD);
  k_transpose_bf<<<dim3(HD / 32, HD / 32), tblk, 0, stream>>>(gat_wr, wt_g1, HD, HD);
  k_transpose_bf<<<dim3(HD / 32, HD / 32), tblk, 0, stream>>>(gat_wr + (size_t)HD * HD, wt_g2, HD, HD);
  k_transpose_bf<<<dim3(HD / 32, HD / 32), tblk, 0, stream>>>(proj_w1, wt_p1, HD, HD);
  k_transpose_bf<<<dim3(DE / 32, HD / 32), tblk, 0, stream>>>(proj_w2, wt_p2, HD, DE);
  k_transpose_bf<<<dim3(DE / 32, DE / 32), tblk, 0, stream>>>(wq, wt_q, DE, DE);
  k_f2bf<<<dim3((DE * DE + 255) / 256), blk, 0, stream>>>(wk, wkb, (long long)DE * DE);
  k_transpose_bf<<<dim3(DE / 32, DE / 32), tblk, 0, stream>>>(wv, wt_v, DE, DE);
  k_transpose_bf<<<dim3(DE / 32, DE / 32), tblk, 0, stream>>>(wo, wt_o, DE, DE);
  k_transpose_bf<<<dim3(4 * DE / 32, DE / 32), tblk, 0, stream>>>(fw1, wt_f1, DE, 4 * DE);
  k_transpose_bf<<<dim3(DE / 32, 4 * DE / 32), tblk, 0, stream>>>(fw2, wt_f2, 4 * DE, DE);

  k_add_emb<<<dim3(2048), blk, 0, stream>>>(x, ns_emb, big0, (long long)N * DE / 4);
  k_f2bf<<<dim3((QNUM * DE + 255) / 256), blk, 0, stream>>>(queries, qs_bf, (long long)QNUM * DE);
  {
    long long pool = (long long)QNUM * DE * 4 + (long long)QNUM * 4 * DE;
    k_zero<<<dim3(1024), blk, 0, stream>>>(q_f, pool);
    k_zero<<<dim3(2048), blk, 0, stream>>>(T_f, (long long)QR * DE);
  }

  // ---- CSR build ----
  k_zero_u32<<<dim3((N + 255) / 256), blk, 0, stream>>>(cnt, N);
  k_count_dst<<<dim3((TOT + 255) / 256), blk, 0, stream>>>(ei, E, TOT, cnt);
  k_scan<<<dim3(1), dim3(1024), 0, stream>>>(cnt, N, rowptr);
  k_zero_u32<<<dim3((N + 255) / 256), blk, 0, stream>>>(cnt, N);
  k_scatter<<<dim3((TOT + 255) / 256), blk, 0, stream>>>(ei, E, TOT, rowptr, cnt, esrc);

  // ---- GAT layers ----
  const bf16* gw[3] = { wt_g0, wt_g1, wt_g2 };
  for (int l = 0; l < 3; l++) {
    const bf16* Ain = (l == 0) ? big0 : hB;
    int Kd = (l == 0) ? DE : HD;
    k_gemm256<0,0,1><<<dim3(2, MT2), dim3(512), 0, stream>>>(Ain, gw[l], nullptr, hhA,
        8, N, HD, HD, Kd, Kd, Kd, HD, 0, 0, 0, 0);
    k_esed<<<dim3(N), dim3(512), 0, stream>>>(hhA, a_src + l * HD, a_dst + l * HD, es, edv);
    if (l < 2)
      k_gat_aggr<2><<<dim3((N + 3) / 4), blk, 0, stream>>>(rowptr, esrc, hhA, es, edv,
          gat_b + l * HD, hB, N);
    else
      k_gat_aggr<0><<<dim3((N + 3) / 4), blk, 0, stream>>>(rowptr, esrc, hhA, es, edv,
          gat_b + l * HD, hB, N);
  }

  // ---- projection -> hD (big0) ----
  k_gemm256<1,1,1><<<dim3(2, MT2), dim3(512), 0, stream>>>(hB, wt_p1, proj_b1, hhA,
      8, N, HD, HD, HD, HD, HD, HD, 0, 0, 0, 0);
  k_gemm256<0,1,1><<<dim3(10, MT2), dim3(512), 0, stream>>>(hhA, wt_p2, proj_b2, big0,
      8, N, DE, DE, HD, HD, HD, DE, 0, 0, 0, 0);

  // hDT = hD^T [DE][NPAD], pad rows zeroed
  k_transpose_h<<<dim3(NPAD / 32, DE / 32), tblk, 0, stream>>>(big0, hDT, N);

  // ---- q projection (split-K atomic) -> q_bf ----
  k_gemm_nt<0,0,2,0><<<dim3(20, 2, 8), blk, 0, stream>>>(qs_bf, wt_q, nullptr, q_f,
      QNUM, DE, DE, DE, DE, DE, 0, 0, 0, 8, 320);
  k_postproc<0,1,1><<<dim3((QNUM * DE + 255) / 256), blk, 0, stream>>>(q_f, bq, q_bf,
      (long long)QNUM * DE, DE);

  // ---- QK_h = q_h @ Wk_h^T  (batched over heads; bk drops out of softmax) ----
  k_gemm_nt<0,0,1,0><<<dim3(20, 2, 8), blk, 0, stream>>>(q_bf, wkb, nullptr, QK_bf,
      QNUM, DE, ADHD, DE, DE, DE, ADHD, ADHD, (long long)QNUM * DE, 1, ADHD);

  // ---- scores = QK[1600,2560] @ hD^T  (256-tile; B = hD as stored) ----
  k_gemm256<0,0,1><<<dim3((NPAD + 255) / 256, (QR + 255) / 256), dim3(512), 0, stream>>>(
      QK_bf, big0, nullptr, sc, 8, QR, NPAD, N, DE, DE, DE, NPAD, 0, 0, 0, 0);
  k_softmax_row<<<dim3(QR), blk, 0, stream>>>(sc, N);

  // ---- T = attn[1600,NPAD] @ hD  (128-tile, split-K=6, f32 atomic accumulate) ----
  k_gemm_nt<0,0,2,0><<<dim3(20, 13, 6), blk, 0, stream>>>(sc, hDT, nullptr, T_f,
      QR, DE, NPAD, NPAD, NPAD, DE, 0, 0, 0, 6, 5024);
  k_postproc<0,0,1><<<dim3((QR * DE + 255) / 256), blk, 0, stream>>>(T_f, nullptr, T_bf,
      (long long)QR * DE, DE);

  // ---- ctx_h = T_h @ Wv_h (+bv via rowsum(attn)=1) ----
  k_gemm_nt<0,0,2,0><<<dim3(3, 2, 8 * 8), blk, 0, stream>>>(T_bf, wt_v, nullptr, ctx_f,
      QNUM, ADHD, DE, DE, DE, DE, (long long)QNUM * DE, (long long)ADHD * DE, ADHD, 8, 320);
  k_postproc<0,1,1><<<dim3((QNUM * DE + 255) / 256), blk, 0, stream>>>(ctx_f, bv, ctx_bf,
      (long long)QNUM * DE, DE);

  // ---- output projection + LN1 ----
  k_gemm_nt<0,0,2,0><<<dim3(20, 2, 8), blk, 0, stream>>>(ctx_bf, wt_o, nullptr, attnout,
      QNUM, DE, DE, DE, DE, DE, 0, 0, 0, 8, 320);
  k_postproc<0,1,0><<<dim3((QNUM * DE + 255) / 256), blk, 0, stream>>>(attnout, bo, nullptr,
      (long long)QNUM * DE, DE);
  k_ln<1><<<dim3(QNUM), blk, 0, stream>>>(queries, attnout, ln1g, ln1b, attended, att_bf);

  // ---- FFN + LN2 ----
  k_gemm_nt<0,0,2,0><<<dim3(80, 2, 4), blk, 0, stream>>>(att_bf, wt_f1, nullptr, f1_f,
      QNUM, 4 * DE, DE, DE, DE, 4 * DE, 0, 0, 0, 4, 640);
  k_postproc<1,1,1><<<dim3((QNUM * 4 * DE + 255) / 256), blk, 0, stream>>>(f1_f, fb1, f1_bf,
      (long long)QNUM * 4 * DE, 4 * DE);
  k_gemm_nt<0,0,2,0><<<dim3(20, 2, 8), blk, 0, stream>>>(f1_bf, wt_f2, nullptr, f2_f,
      QNUM, DE, 4 * DE, 4 * DE, 4 * DE, DE, 0, 0, 0, 8, 1280);
  k_postproc<0,1,0><<<dim3((QNUM * DE + 255) / 256), blk, 0, stream>>>(f2_f, fb2, nullptr,
      (long long)QNUM * DE, DE);
  k_ln<0><<<dim3(QNUM), blk, 0, stream>>>(attended, f2_f, ln2g, ln2b, out, nullptr);
}

// Round 12
// 1818.252 us; speedup vs baseline: 1.0288x; 1.0288x over previous
//
#include <hip/hip_runtime.h>
#include <hip/hip_bf16.h>
#include <cmath>

typedef __hip_bfloat16 bf16;
typedef __attribute__((ext_vector_type(8))) short short8;
typedef __attribute__((ext_vector_type(4))) short short4_t;
typedef __attribute__((ext_vector_type(4))) float f32x4;
typedef __attribute__((address_space(1))) void as1_void;
typedef __attribute__((address_space(3))) void as3_void;

#define DE   2560
#define HD   512
#define NPAD 30016
#define QNUM 200
#define ADHD 320
#define QR   1600   // 8 heads * 200 q-rows

static __device__ __forceinline__ float bf2f(bf16 v){ return __bfloat162float(v); }
static __device__ __forceinline__ bf16  f2bf(float v){ return __float2bfloat16(v); }
static __device__ __forceinline__ short bfbits(float f){ bf16 b = f2bf(f); return *reinterpret_cast<short*>(&b); }
static __device__ __forceinline__ float geluf(float x){ return 0.5f*x*(1.0f+erff(x*0.70710678118654752440f)); }
static __device__ __forceinline__ float eluf(float x){ return x>0.f ? x : expm1f(x); }

static __device__ __forceinline__ void gload16(const void* g, void* l){
  __builtin_amdgcn_global_load_lds((as1_void*)g, (as3_void*)l, 16, 0, 0);
}

// =================== 256x256 8-phase bf16 NT GEMM (R4-proven loop) ==========
// C[M,N] = act(A[M,K]*B[N,K]^T + bias). BK=64, 512 thr (8 waves 2Mx4N), 128KB
// LDS dbuf. OBF: 1 = bf16 LDS-retiled store, 0 = f32 direct, 2 = f32 atomicAdd.
template<int ACT, int BIAS, int OBF>
__global__ __launch_bounds__(512, 1)
void k_gemm256(const bf16* __restrict__ A, const bf16* __restrict__ B,
               const float* __restrict__ bias, void* __restrict__ Cv,
               int gm, int M, int N, int NB, int K, int lda, int ldb, int ldc,
               long long sA, long long sB, long long sC, int ks)
{
  __shared__ __align__(16) char smem[131072];   // A:[2][32KB] @0, B:[2][32KB] @64KB
  const int bz = blockIdx.z;
  const bf16* Ab = A + (long long)bz * sA;
  const bf16* Bb = B + (long long)bz * sB;
  const long long cbase = (long long)bz * sC;
  int kbeg = 0, kend = K;
  if (ks > 0) { kbeg = bz * ks; kend = kbeg + ks; if (kend > K) kend = K; }

  // block swizzle: XCD-bijective then gm-supertile over M
  const int gx = gridDim.x, gy = gridDim.y;
  const int nwg = gx * gy;
  int orig = blockIdx.y * gx + blockIdx.x;
  {
    const int q8 = nwg >> 3, r8 = nwg & 7;
    const int xcd = orig & 7, idx = orig >> 3;
    orig = (xcd < r8 ? xcd * (q8 + 1) : r8 * (q8 + 1) + (xcd - r8) * q8) + idx;
  }
  const int per_g = gm * gx;
  const int g = orig / per_g, rem = orig - g * per_g;
  int gsz = gy - g * gm; if (gsz > gm) gsz = gm;
  const int mi = g * gm + rem % gsz;
  const int ni = rem / gsz;
  const int m0 = mi * 256, n0 = ni * 256;

  const int tid = threadIdx.x, lane = tid & 63, wave = tid >> 6;
  const int wm = (wave >> 2) * 128, wn = (wave & 3) * 64;
  const int fr = lane & 15, fg = lane >> 4;
  const int cS0 = ((fg) ^ (fr & 7)) * 16;
  const int cS1 = ((4 + fg) ^ (fr & 7)) * 16;

  const bf16* pA[2][2]; const bf16* pB[2][2];
  #pragma unroll
  for (int L = 0; L < 2; L++) {
    const int ch = L * 512 + tid;
    const int lr = ch >> 3;
    #pragma unroll
    for (int mh = 0; mh < 2; mh++) {
      int r = (lr & 63) + mh * 64 + ((lr & 64) << 1);
      int cs = (ch & 7) ^ (r & 7);
      int gr = m0 + r; if (gr > M - 1) gr = M - 1;
      pA[mh][L] = Ab + (long long)gr * lda + cs * 8;
    }
    #pragma unroll
    for (int nh = 0; nh < 2; nh++) {
      int r = nh * 32 + (lr & 31) + ((lr >> 5) << 6);
      int cs = (ch & 7) ^ (r & 7);
      int gr = n0 + r; if (gr > NB - 1) gr = NB - 1;
      pB[nh][L] = Bb + (long long)gr * ldb + cs * 8;
    }
  }

  #define STG_A(mh, buf, kk) do {                                        \
    char* d_ = smem + (buf) * 32768 + ((mh) * 64 + wave * 8) * 128;      \
    gload16(pA[mh][0] + (kk), d_);                                       \
    gload16(pA[mh][1] + (kk), d_ + 16384);                               \
  } while (0)
  #define STG_B(nh, buf, kk) do {                                        \
    char* d_ = smem + 65536 + (buf) * 32768 +                            \
               ((nh) * 32 + (wave & 3) * 8 + (wave >> 2) * 64) * 128;    \
    gload16(pB[nh][0] + (kk), d_);                                       \
    gload16(pB[nh][1] + (kk), d_ + 16384);                               \
  } while (0)

  f32x4 acc[8][4];
  #pragma unroll
  for (int i = 0; i < 8; i++)
    #pragma unroll
    for (int j = 0; j < 4; j++) acc[i][j] = (f32x4){0.f, 0.f, 0.f, 0.f};

  const int nt = (kend - kbeg) / 64;
  // prologue: tile 0 -> buf 0, granule NEED-order A0,B0,B1,A1
  STG_A(0, 0, kbeg); STG_B(0, 0, kbeg); STG_B(1, 0, kbeg); STG_A(1, 0, kbeg);

  #define LOAD_A(mh) do {                                                \
    _Pragma("unroll")                                                    \
    for (int i = 0; i < 4; i++) {                                        \
      const char* p_ = Ab_l + (wm + (mh) * 64 + i * 16 + fr) * 128;      \
      a_[i][0] = *(const short8*)(p_ + cS0);                             \
      a_[i][1] = *(const short8*)(p_ + cS1);                             \
    }                                                                    \
  } while (0)
  #define LOAD_B(nh) do {                                                \
    _Pragma("unroll")                                                    \
    for (int j = 0; j < 2; j++) {                                        \
      const char* p_ = Bb_l + (wn + (nh) * 32 + j * 16 + fr) * 128;      \
      b_[j][0] = *(const short8*)(p_ + cS0);                             \
      b_[j][1] = *(const short8*)(p_ + cS1);                             \
    }                                                                    \
  } while (0)
  #define MFMA_Q(mh, nh) do {                                            \
    __builtin_amdgcn_s_setprio(1);                                       \
    _Pragma("unroll")                                                    \
    for (int i = 0; i < 4; i++)                                          \
      _Pragma("unroll")                                                  \
      for (int j = 0; j < 2; j++) {                                      \
        acc[(mh)*4+i][(nh)*2+j] = __builtin_amdgcn_mfma_f32_16x16x32_bf16( \
            a_[i][0], b_[j][0], acc[(mh)*4+i][(nh)*2+j], 0, 0, 0);       \
        acc[(mh)*4+i][(nh)*2+j] = __builtin_amdgcn_mfma_f32_16x16x32_bf16( \
            a_[i][1], b_[j][1], acc[(mh)*4+i][(nh)*2+j], 0, 0, 0);       \
      }                                                                  \
    __builtin_amdgcn_s_setprio(0);                                       \
  } while (0)

  for (int t = 0; t < nt; t++) {
    const int buf = t & 1, nb = buf ^ 1;
    const int kn = kbeg + (t + 1) * 64;
    const bool pf = (t + 1 < nt);
    const char* Ab_l = smem + buf * 32768;
    const char* Bb_l = smem + 65536 + buf * 32768;
    short8 a_[4][2], b_[2][2];

    asm volatile("s_waitcnt vmcnt(4)" ::: "memory");
    __builtin_amdgcn_s_barrier();
    LOAD_A(0); LOAD_B(0);
    if (pf) STG_A(0, nb, kn);
    MFMA_Q(0, 0);

    if (pf) { asm volatile("s_waitcnt vmcnt(4)" ::: "memory"); }
    else    { asm volatile("s_waitcnt vmcnt(2)" ::: "memory"); }
    __builtin_amdgcn_s_barrier();
    LOAD_B(1);
    if (pf) STG_B(0, nb, kn);
    MFMA_Q(0, 1);

    if (pf) { asm volatile("s_waitcnt vmcnt(4)" ::: "memory"); }
    else    { asm volatile("s_waitcnt vmcnt(0)" ::: "memory"); }
    __builtin_amdgcn_s_barrier();
    LOAD_A(1);
    if (pf) STG_B(1, nb, kn);
    MFMA_Q(1, 1);

    __builtin_amdgcn_s_barrier();
    LOAD_B(0);
    if (pf) STG_A(1, nb, kn);
    MFMA_Q(1, 0);
  }
  #undef LOAD_A
  #undef LOAD_B
  #undef MFMA_Q
  #undef STG_A
  #undef STG_B

  // ---- epilogue ----
  asm volatile("s_waitcnt vmcnt(0)" ::: "memory");
  __builtin_amdgcn_s_barrier();
  float bv_[4];
  #pragma unroll
  for (int j = 0; j < 4; j++) {
    int c = n0 + wn + j * 16 + fr;
    bv_[j] = (BIAS && c < N) ? bias[c] : 0.f;
  }

  if (OBF == 0 || OBF == 2) {
    float* Cf = (float*)Cv;
    #pragma unroll
    for (int i = 0; i < 8; i++)
      #pragma unroll
      for (int j = 0; j < 4; j++) {
        const int col = n0 + wn + j * 16 + fr;
        if (col >= N) continue;
        #pragma unroll
        for (int r = 0; r < 4; r++) {
          const int row = m0 + wm + i * 16 + fg * 4 + r;
          if (row >= M) continue;
          float v = acc[i][j][r];
          if (BIAS) v += bv_[j];
          if (OBF == 2) atomicAdd(&Cf[cbase + (long long)row * ldc + col], v);
          else          Cf[cbase + (long long)row * ldc + col] = v;
        }
      }
  } else {
    bf16* Cb = (bf16*)Cv;
    bf16* epi = (bf16*)(smem + wave * 16384);   // [128 rows][64 cols]
    #pragma unroll
    for (int i = 0; i < 8; i++)
      #pragma unroll
      for (int j = 0; j < 4; j++)
        #pragma unroll
        for (int r = 0; r < 4; r++) {
          float v = acc[i][j][r];
          if (BIAS) v += bv_[j];
          if (ACT == 1) v = geluf(v);
          else if (ACT == 2) v = eluf(v);
          epi[(i * 16 + fg * 4 + r) * 64 + j * 16 + fr] = f2bf(v);
        }
    #pragma unroll
    for (int it = 0; it < 16; it++) {
      int lrow = it * 8 + (lane >> 3);
      int grow = m0 + wm + lrow;
      int gcol = n0 + wn + (lane & 7) * 8;
      if (grow < M && gcol < N)
        *(short8*)(Cb + cbase + (long long)grow * ldc + gcol) =
            *(const short8*)(epi + lrow * 64 + (lane & 7) * 8);
    }
  }
}

// ---------------- 128-tile NT GEMM (small-M / short-K / batched / split-K) ----------------
template<int ACT, int BIAS, int OBF, int TROUT>
__global__ __launch_bounds__(256)
void k_gemm_nt(const bf16* __restrict__ A, const bf16* __restrict__ B,
               const float* __restrict__ bias, void* __restrict__ Cv,
               int M, int N, int K, int lda, int ldb, int ldc,
               long long sA, long long sB, long long sC, int nsplit, int ks)
{
  __shared__ __align__(16) bf16 As[3][128*32];
  __shared__ __align__(16) bf16 Bs[3][128*32];
  const int zb = blockIdx.z;
  const int b  = zb / nsplit;
  const int sl = zb - b*nsplit;
  const int kbeg = sl * ks;
  int kend = kbeg + ks; if (kend > K) kend = K;
  const int nt = (kend > kbeg) ? (kend - kbeg + 31) / 32 : 0;

  const bf16* Ab = A + (long long)b * sA;
  const bf16* Bb = B + (long long)b * sB;
  const long long cbase = (long long)b * sC;

  const int NTt = gridDim.x, MTt = gridDim.y;
  const int nwg = NTt * MTt;
  int orig = blockIdx.y * NTt + blockIdx.x;
  {
    const int q8 = nwg >> 3, r8 = nwg & 7;
    const int xcd = orig & 7, idx = orig >> 3;
    orig = (xcd < r8 ? xcd * (q8 + 1) : r8 * (q8 + 1) + (xcd - r8) * q8) + idx;
  }
  const int GM = 8;
  const int per_g = GM * NTt;
  const int g = orig / per_g, rem = orig - g * per_g;
  int gsz = MTt - g * GM; if (gsz > GM) gsz = GM;
  const int mi = g * GM + rem % gsz;
  const int ni = rem / gsz;

  const int m0 = mi * 128, n0 = ni * 128;
  const int tid = threadIdx.x, lane = tid & 63, wave = tid >> 6;
  const int wm = (wave >> 1) * 64, wn = (wave & 1) * 64;
  const int fr = lane & 15, fg = lane >> 4;
  const int fgs = fg ^ ((fr >> 1) & 3);

  f32x4 acc[4][4];
  #pragma unroll
  for (int i = 0; i < 4; i++)
    #pragma unroll
    for (int j = 0; j < 4; j++) acc[i][j] = (f32x4){0.f, 0.f, 0.f, 0.f};

  const int c0 = wave * 128 + lane;
  const int c1 = c0 + 64;
  const int rA0 = c0 >> 2, rA1 = c1 >> 2;
  const int cc0 = ((c0 & 3) ^ ((rA0 >> 1) & 3)) * 8;
  const int cc1 = ((c1 & 3) ^ ((rA1 >> 1) & 3)) * 8;
  int gra0 = m0 + rA0; if (gra0 >= M) gra0 = M - 1;
  int gra1 = m0 + rA1; if (gra1 >= M) gra1 = M - 1;
  int grb0 = n0 + rA0; if (grb0 >= N) grb0 = N - 1;
  int grb1 = n0 + rA1; if (grb1 >= N) grb1 = N - 1;
  const bf16* pa0 = Ab + (long long)gra0 * lda + cc0;
  const bf16* pa1 = Ab + (long long)gra1 * lda + cc1;
  const bf16* pb0 = Bb + (long long)grb0 * ldb + cc0;
  const bf16* pb1 = Bb + (long long)grb1 * ldb + cc1;

  char* lA = (char*)&As[0][0] + wave * 2048;
  char* lB = (char*)&Bs[0][0] + wave * 2048;

  #define STAGE(buf, kk) do {                       \
    char* a_ = lA + (buf) * 8192;                   \
    char* b_ = lB + (buf) * 8192;                   \
    gload16(pa0 + (kk), a_);                        \
    gload16(pa1 + (kk), a_ + 1024);                 \
    gload16(pb0 + (kk), b_);                        \
    gload16(pb1 + (kk), b_ + 1024);                 \
  } while (0)

  if (nt > 0) STAGE(0, kbeg);
  if (nt > 1) STAGE(1, kbeg + 32);

  int cur = 0;
  for (int t = 0; t < nt; t++) {
    if (t + 2 < nt) {
      int n2 = cur + 2; if (n2 >= 3) n2 -= 3;
      STAGE(n2, kbeg + (t + 2) * 32);
      asm volatile("s_waitcnt vmcnt(8)" ::: "memory");
    } else if (t + 1 < nt) {
      asm volatile("s_waitcnt vmcnt(4)" ::: "memory");
    } else {
      asm volatile("s_waitcnt vmcnt(0)" ::: "memory");
    }
    __builtin_amdgcn_s_barrier();

    const bf16* Asb = (const bf16*)((const char*)&As[0][0] + cur * 8192);
    const bf16* Bsb = (const bf16*)((const char*)&Bs[0][0] + cur * 8192);
    short8 af[4], bfv[4];
    #pragma unroll
    for (int i = 0; i < 4; i++) {
      af[i]  = *(const short8*)(Asb + (wm + i * 16 + fr) * 32 + fgs * 8);
      bfv[i] = *(const short8*)(Bsb + (wn + i * 16 + fr) * 32 + fgs * 8);
    }
    #pragma unroll
    for (int i = 0; i < 4; i++)
      #pragma unroll
      for (int j = 0; j < 4; j++)
        acc[i][j] = __builtin_amdgcn_mfma_f32_16x16x32_bf16(af[i], bfv[j], acc[i][j], 0, 0, 0);

    asm volatile("s_waitcnt lgkmcnt(0)" ::: "memory");
    __builtin_amdgcn_s_barrier();
    cur = cur + 1; if (cur >= 3) cur = 0;
  }
  #undef STAGE

  #pragma unroll
  for (int i = 0; i < 4; i++) {
    const int r0 = m0 + wm + i * 16 + fg * 4;
    #pragma unroll
    for (int j = 0; j < 4; j++) {
      const int col = n0 + wn + j * 16 + fr;
      if (col >= N) continue;
      float bv = 0.f;
      if (BIAS) bv = bias[col];
      #pragma unroll
      for (int r = 0; r < 4; r++) {
        const int row = r0 + r;
        if (row >= M) continue;
        float v = acc[i][j][r] + bv;
        if (ACT == 1) v = geluf(v);
        else if (ACT == 2) v = eluf(v);
        long long off;
        if (TROUT) off = cbase + (long long)col * ldc + row;
        else       off = cbase + (long long)row * ldc + col;
        if (OBF == 1)      ((bf16*)Cv)[off] = f2bf(v);
        else if (OBF == 2) atomicAdd(&((float*)Cv)[off], v);
        else               ((float*)Cv)[off] = v;
      }
    }
  }
}

// ---------------- small utility kernels ----------------
__global__ void k_zero(float* p, long long n) {
  long long i = (long long)blockIdx.x * blockDim.x + threadIdx.x;
  long long st = (long long)gridDim.x * blockDim.x;
  for (; i < n; i += st) p[i] = 0.f;
}

__global__ void k_zero_u32(unsigned* p, int n) {
  int i = blockIdx.x * 256 + threadIdx.x;
  if (i < n) p[i] = 0u;
}

__global__ void k_f2bf(const float* __restrict__ in, bf16* __restrict__ out, long long n) {
  long long i = (long long)blockIdx.x * 256 + threadIdx.x;
  if (i < n) out[i] = f2bf(in[i]);
}

__global__ void k_add_emb(const float* __restrict__ x, const float* __restrict__ ns,
                          bf16* __restrict__ h0, long long n4) {
  long long i = (long long)blockIdx.x * 256 + threadIdx.x;
  long long st = (long long)gridDim.x * 256;
  for (; i < n4; i += st) {
    float4 v = ((const float4*)x)[i];
    int d = (int)(i % (DE / 4)) * 4;
    short4_t o;
    o.x = bfbits(v.x + ns[d]);
    o.y = bfbits(v.y + ns[d + 1]);
    o.z = bfbits(v.z + ns[d + 2]);
    o.w = bfbits(v.w + ns[d + 3]);
    ((short4_t*)h0)[i] = o;
  }
}

// transpose f32 [R,C] -> bf16 [C,R]; R,C multiples of 32
__global__ void k_transpose_bf(const float* __restrict__ W, bf16* __restrict__ Wt, int R, int C) {
  __shared__ float t[32][33];
  int c0 = blockIdx.x * 32, r0 = blockIdx.y * 32;
  int x = threadIdx.x, y = threadIdx.y;
  #pragma unroll
  for (int j = 0; j < 32; j += 8)
    t[y + j][x] = W[(long long)(r0 + y + j) * C + c0 + x];
  __syncthreads();
  #pragma unroll
  for (int j = 0; j < 32; j += 8)
    Wt[(long long)(c0 + y + j) * R + r0 + x] = f2bf(t[x][y + j]);
}

// transpose bf16 src[Nv][DE] -> dst[DE][NPAD], zero-fill rows >= Nv
__global__ void k_transpose_h(const bf16* __restrict__ src, bf16* __restrict__ dst, int Nv) {
  __shared__ bf16 t[32][34];
  int n0 = blockIdx.x * 32, d0 = blockIdx.y * 32;
  int x = threadIdx.x, y = threadIdx.y;
  #pragma unroll
  for (int j = 0; j < 32; j += 8) {
    int n = n0 + y + j;
    t[y + j][x] = (n < Nv) ? src[(long long)n * DE + d0 + x] : f2bf(0.f);
  }
  __syncthreads();
  #pragma unroll
  for (int j = 0; j < 32; j += 8)
    dst[(long long)(d0 + y + j) * NPAD + n0 + x] = t[x][y + j];
}

// ---- CSR build (dst-indexed) ----
__global__ void k_count_dst(const int* __restrict__ ei, int E, int TOT, unsigned* __restrict__ cnt) {
  int e = blockIdx.x * 256 + threadIdx.x;
  if (e >= TOT) return;
  int d = (e < E) ? ei[E + e] : (e - E);
  atomicAdd(&cnt[d], 1u);
}

__global__ __launch_bounds__(1024)
void k_scan(const unsigned* __restrict__ cnt, int n, int* __restrict__ rowptr) {
  __shared__ unsigned tot[1024];
  int t = threadIdx.x;
  int ch = (n + 1023) / 1024;
  int beg = t * ch, end = beg + ch; if (end > n) end = n; if (beg > n) beg = n;
  unsigned s = 0;
  for (int i = beg; i < end; i++) s += cnt[i];
  tot[t] = s;
  __syncthreads();
  for (int o = 1; o < 1024; o <<= 1) {
    unsigned u = (t >= o) ? tot[t - o] : 0u;
    __syncthreads();
    tot[t] += u;
    __syncthreads();
  }
  unsigned run = tot[t] - s;
  for (int i = beg; i < end; i++) { rowptr[i] = (int)run; run += cnt[i]; }
  if (t == 1023) rowptr[n] = (int)tot[1023];
}

__global__ void k_scatter(const int* __restrict__ ei, int E, int TOT,
                          const int* __restrict__ rowptr, unsigned* __restrict__ cursor,
                          int* __restrict__ esrc) {
  int e = blockIdx.x * 256 + threadIdx.x;
  if (e >= TOT) return;
  int s, d;
  if (e < E) { s = ei[e]; d = ei[E + e]; } else { s = d = e - E; }
  unsigned pos = atomicAdd(&cursor[d], 1u);
  esrc[rowptr[d] + pos] = s;
}

// es/ed per node: block = 512 threads, wave w = head
__global__ __launch_bounds__(512)
void k_esed(const bf16* __restrict__ hh, const float* __restrict__ asrc,
            const float* __restrict__ adst, float* __restrict__ es, float* __restrict__ ed) {
  int n = blockIdx.x;
  int h = threadIdx.x >> 6;
  int c = threadIdx.x & 63;
  float v = bf2f(hh[(long long)n * HD + h * 64 + c]);
  float s = v * asrc[h * 64 + c];
  float d = v * adst[h * 64 + c];
  #pragma unroll
  for (int o = 32; o; o >>= 1) { s += __shfl_down(s, o, 64); d += __shfl_down(d, o, 64); }
  if (c == 0) { es[n * 8 + h] = s; ed[n * 8 + h] = d; }
}

// fused GAT aggregation: one wave per destination node; 2-edge unrolled gather.
template<int ACT>
__global__ __launch_bounds__(256)
void k_gat_aggr(const int* __restrict__ rowptr, const int* __restrict__ esrc,
                const bf16* __restrict__ hh, const float* __restrict__ es,
                const float* __restrict__ ed, const float* __restrict__ gb,
                bf16* __restrict__ outp, int Nn)
{
  int w = blockIdx.x * 4 + (threadIdx.x >> 6);
  if (w >= Nn) return;
  int lane = threadIdx.x & 63;
  int h = lane >> 3;
  int beg = rowptr[w], end = rowptr[w + 1];
  float edh = ed[w * 8 + h];
  float mx = -3.0e38f;
  for (int e = beg; e < end; e++) {
    int s = esrc[e];
    float l = es[s * 8 + h] + edh;
    l = l > 0.f ? l : 0.2f * l;
    mx = fmaxf(mx, l);
  }
  float den = 0.f;
  float acc[8] = {0.f, 0.f, 0.f, 0.f, 0.f, 0.f, 0.f, 0.f};
  int e = beg;
  for (; e + 1 < end; e += 2) {
    int s0 = esrc[e], s1 = esrc[e + 1];
    float l0 = es[s0 * 8 + h] + edh; l0 = l0 > 0.f ? l0 : 0.2f * l0;
    float l1 = es[s1 * 8 + h] + edh; l1 = l1 > 0.f ? l1 : 0.2f * l1;
    float ex0 = expf(l0 - mx), ex1 = expf(l1 - mx);
    den += ex0 + ex1;
    short8 v0 = *(const short8*)(hh + (long long)s0 * HD + lane * 8);
    short8 v1 = *(const short8*)(hh + (long long)s1 * HD + lane * 8);
    #pragma unroll
    for (int j = 0; j < 8; j++) {
      short a0 = v0[j], a1 = v1[j];
      acc[j] += ex0 * bf2f(*reinterpret_cast<bf16*>(&a0))
              + ex1 * bf2f(*reinterpret_cast<bf16*>(&a1));
    }
  }
  if (e < end) {
    int s = esrc[e];
    float l = es[s * 8 + h] + edh; l = l > 0.f ? l : 0.2f * l;
    float ex = expf(l - mx);
    den += ex;
    short8 v = *(const short8*)(hh + (long long)s * HD + lane * 8);
    #pragma unroll
    for (int j = 0; j < 8; j++) {
      short a = v[j];
      acc[j] += ex * bf2f(*reinterpret_cast<bf16*>(&a));
    }
  }
  float rs = 1.f / (den + 1e-16f);
  short8 o;
  #pragma unroll
  for (int j = 0; j < 8; j++) {
    float val = acc[j] * rs + gb[lane * 8 + j];
    if (ACT == 2) val = eluf(val);
    o[j] = bfbits(val);
  }
  *(short8*)(outp + (long long)w * HD + lane * 8) = o;
}

template<int ACT, int BIAS, int TOBF>
__global__ void k_postproc(float* __restrict__ acc, const float* __restrict__ bias,
                           bf16* __restrict__ obf, long long tot, int cols) {
  long long i = (long long)blockIdx.x * 256 + threadIdx.x;
  if (i >= tot) return;
  int c = (int)(i % cols);
  float v = acc[i];
  if (BIAS) v += bias[c];
  if (ACT == 1) v = geluf(v);
  if (TOBF) obf[i] = f2bf(v);
  else acc[i] = v;
}

// row softmax (in-place), LDS-cached row: scores bf16 [rows][NPAD], scale folded
__global__ __launch_bounds__(256)
void k_softmax_row(bf16* s_all, int NV) {
  __shared__ __align__(16) bf16 srow[NPAD];   // 60 KB -> 2 blocks/CU
  __shared__ float red[4];
  long long row = blockIdx.x;
  bf16* s = s_all + row * NPAD;
  int tid = threadIdx.x;
  for (int c = tid * 8; c < NV; c += 2048)
    *(short8*)(srow + c) = *(const short8*)(s + c);
  __syncthreads();
  float mx = -3.0e38f;
  for (int c = tid; c < NV; c += 256) mx = fmaxf(mx, bf2f(srow[c]));
  #pragma unroll
  for (int o = 32; o; o >>= 1) mx = fmaxf(mx, __shfl_down(mx, o, 64));
  if ((tid & 63) == 0) red[tid >> 6] = mx;
  __syncthreads();
  mx = fmaxf(fmaxf(red[0], red[1]), fmaxf(red[2], red[3]));
  const float inv = 0.05590169943749474f;  // 1/sqrt(320)
  float sm = 0.f;
  for (int c = tid; c < NV; c += 256) sm += expf((bf2f(srow[c]) - mx) * inv);
  #pragma unroll
  for (int o = 32; o; o >>= 1) sm += __shfl_down(sm, o, 64);
  __syncthreads();
  if ((tid & 63) == 0) red[tid >> 6] = sm;
  __syncthreads();
  sm = red[0] + red[1] + red[2] + red[3];
  float rs = 1.f / sm;
  for (int c = tid * 8; c < NPAD; c += 2048) {
    short8 o;
    #pragma unroll
    for (int j = 0; j < 8; j++) {
      int cc = c + j;
      float v = (cc < NV) ? expf((bf2f(srow[cc]) - mx) * inv) * rs : 0.f;
      o[j] = bfbits(v);
    }
    *(short8*)(s + c) = o;
  }
}

// LayerNorm(a+b) row of DE, optional bf16 dup
template<int WB>
__global__ __launch_bounds__(256)
void k_ln(const float* __restrict__ a, const float* __restrict__ b,
          const float* __restrict__ g, const float* __restrict__ bt,
          float* __restrict__ out, bf16* __restrict__ obf) {
  long long row = blockIdx.x;
  __shared__ float xs[DE];
  __shared__ float red[4];
  int tid = threadIdx.x;
  float sum = 0.f;
  for (int c = tid; c < DE; c += 256) {
    float v = a[row * DE + c] + b[row * DE + c];
    xs[c] = v; sum += v;
  }
  #pragma unroll
  for (int o = 32; o; o >>= 1) sum += __shfl_down(sum, o, 64);
  if ((tid & 63) == 0) red[tid >> 6] = sum;
  __syncthreads();
  float mean = (red[0] + red[1] + red[2] + red[3]) * (1.f / DE);
  float vs = 0.f;
  for (int c = tid; c < DE; c += 256) { float t = xs[c] - mean; vs += t * t; }
  #pragma unroll
  for (int o = 32; o; o >>= 1) vs += __shfl_down(vs, o, 64);
  __syncthreads();
  if ((tid & 63) == 0) red[tid >> 6] = vs;
  __syncthreads();
  float var = (red[0] + red[1] + red[2] + red[3]) * (1.f / DE);
  float sc = rsqrtf(var + 1e-5f);
  for (int c = tid; c < DE; c += 256) {
    float v = (xs[c] - mean) * sc * g[c] + bt[c];
    out[row * DE + c] = v;
    if (WB) obf[row * DE + c] = f2bf(v);
  }
}

// ---------------- host ----------------
extern "C" void kernel_launch(void* const* d_in, const int* in_sizes, int n_in,
                              void* d_out, int out_size, void* d_ws, size_t ws_size,
                              hipStream_t stream)
{
  const float* x       = (const float*)d_in[0];
  const int*   ei      = (const int*)d_in[1];
  const float* ns_emb  = (const float*)d_in[2];
  const float* gat_w0  = (const float*)d_in[3];
  const float* gat_wr  = (const float*)d_in[4];
  const float* a_src   = (const float*)d_in[5];
  const float* a_dst   = (const float*)d_in[6];
  const float* gat_b   = (const float*)d_in[7];
  const float* proj_w1 = (const float*)d_in[8];
  const float* proj_b1 = (const float*)d_in[9];
  const float* proj_w2 = (const float*)d_in[10];
  const float* proj_b2 = (const float*)d_in[11];
  const float* queries = (const float*)d_in[12];
  const float* wq = (const float*)d_in[13]; const float* bq = (const float*)d_in[14];
  const float* wk = (const float*)d_in[15];
  const float* wv = (const float*)d_in[17]; const float* bv = (const float*)d_in[18];
  const float* wo = (const float*)d_in[19]; const float* bo = (const float*)d_in[20];
  const float* ln1g = (const float*)d_in[21]; const float* ln1b = (const float*)d_in[22];
  const float* fw1 = (const float*)d_in[23]; const float* fb1 = (const float*)d_in[24];
  const float* fw2 = (const float*)d_in[25]; const float* fb2 = (const float*)d_in[26];
  const float* ln2g = (const float*)d_in[27]; const float* ln2b = (const float*)d_in[28];
  float* out = (float*)d_out;

  const int N = in_sizes[0] / DE;   // 30000
  const int E = in_sizes[1] / 2;    // 90000
  const int TOT = E + N;            // 120000
  const int MT2 = (N + 255) / 256;  // 118
  const int MT1 = (N + 127) / 128;  // 235

  char* base = (char*)d_ws;
  size_t off = 0;
  auto AL = [&](size_t bytes) -> void* {
    void* p = base + off;
    off += (bytes + 255) & ~(size_t)255;
    return p;
  };
  bf16* wt_g0 = (bf16*)AL((size_t)HD * DE * 2);
  bf16* wt_g1 = (bf16*)AL((size_t)HD * HD * 2);
  bf16* wt_g2 = (bf16*)AL((size_t)HD * HD * 2);
  bf16* wt_p1 = (bf16*)AL((size_t)HD * HD * 2);
  bf16* wt_p2 = (bf16*)AL((size_t)DE * HD * 2);
  bf16* wt_q  = (bf16*)AL((size_t)DE * DE * 2);
  bf16* wkb   = (bf16*)AL((size_t)DE * DE * 2);   // Wk untransposed, bf16
  bf16* wt_v  = (bf16*)AL((size_t)DE * DE * 2);   // Wv^T
  bf16* wt_o  = (bf16*)AL((size_t)DE * DE * 2);
  bf16* wt_f1 = (bf16*)AL((size_t)4 * DE * DE * 2);
  bf16* wt_f2 = (bf16*)AL((size_t)4 * DE * DE * 2);
  bf16* big0  = (bf16*)AL((size_t)N * DE * 2);      // h0 -> hD
  // bigX carve: QK_bf (8.2MB) + T_f (16.4MB) + T_bf (8.2MB) within 153.6MB
  char* bigX  = (char*)AL((size_t)N * DE * 2);
  bf16*  QK_bf = (bf16*)bigX;
  float* T_f   = (float*)(bigX + (size_t)QR * DE * 2);
  bf16*  T_bf  = (bf16*)((char*)T_f + (size_t)QR * DE * 4);
  bf16* hDT   = (bf16*)AL((size_t)DE * NPAD * 2);   // hD transposed, pad rows zeroed
  // GAT scratch block; union'd with scores buffer `sc` (used after GAT dies)
  const size_t scBytes = (size_t)QR * NPAD * 2;     // 96.05 MB
  size_t gatBytes = 2 * (size_t)N * HD * 2 + 2 * (size_t)N * 8 * 4
                  + (size_t)(N + 1) * 4 + (size_t)TOT * 4 + (size_t)N * 4 + 4096;
  char* gat_blk = (char*)AL(gatBytes > scBytes ? gatBytes : scBytes);
  bf16* hhA = (bf16*)gat_blk;
  bf16* hB  = hhA + (size_t)N * HD;
  float* es  = (float*)(hB + (size_t)N * HD);
  float* edv = es + (size_t)N * 8;
  int* rowptr = (int*)(edv + (size_t)N * 8);
  int* esrc   = rowptr + (N + 1);
  unsigned* cnt = (unsigned*)(esrc + TOT);
  bf16* sc = (bf16*)gat_blk;  // scores/attn [QR][NPAD]
  // small f32 pool (zeroed once; targets of split-K atomic GEMMs)
  float* q_f     = (float*)AL((size_t)QNUM * DE * 4);
  float* ctx_f   = (float*)AL((size_t)QNUM * DE * 4);
  float* attnout = (float*)AL((size_t)QNUM * DE * 4);
  float* f1_f    = (float*)AL((size_t)QNUM * 4 * DE * 4);
  float* f2_f    = (float*)AL((size_t)QNUM * DE * 4);
  bf16* qs_bf  = (bf16*)AL((size_t)QNUM * DE * 2);
  bf16* q_bf   = (bf16*)AL((size_t)QNUM * DE * 2);
  bf16* ctx_bf = (bf16*)AL((size_t)QNUM * DE * 2);
  float* attended = (float*)AL((size_t)QNUM * DE * 4);
  bf16* att_bf = (bf16*)AL((size_t)QNUM * DE * 2);
  bf16* f1_bf  = (bf16*)AL((size_t)QNUM * 4 * DE * 2);

  dim3 blk(256);
  dim3 tblk(32, 8);

  // weight prep
  k_transpose_bf<<<dim3(HD / 32, DE / 32), tblk, 0, stream>>>(gat_w0, wt_g0, DE, HD);
  k_transpose_bf<<<dim3(HD / 32, HD / 32), tblk, 0, stream>>>(gat_wr, wt_g1, HD, HD);
  k_transpose_bf<<<dim3(HD / 32, HD / 32), tblk, 0, stream>>>(gat_wr + (size_t)HD * HD, wt_g2, HD, HD);
  k_transpose_bf<<<dim3(HD / 32, HD / 32), tblk, 0, stream>>>(proj_w1, wt_p1, HD, HD);
  k_transpose_bf<<<dim3(DE / 32, HD / 32), tblk, 0, stream>>>(proj_w2, wt_p2, HD, DE);
  k_transpose_bf<<<dim3(DE / 32, DE / 32), tblk, 0, stream>>>(wq, wt_q, DE, DE);
  k_f2bf<<<dim3((DE * DE + 255) / 256), blk, 0, stream>>>(wk, wkb, (long long)DE * DE);
  k_transpose_bf<<<dim3(DE / 32, DE / 32), tblk, 0, stream>>>(wv, wt_v, DE, DE);
  k_transpose_bf<<<dim3(DE / 32, DE / 32), tblk, 0, stream>>>(wo, wt_o, DE, DE);
  k_transpose_bf<<<dim3(4 * DE / 32, DE / 32), tblk, 0, stream>>>(fw1, wt_f1, DE, 4 * DE);
  k_transpose_bf<<<dim3(DE / 32, 4 * DE / 32), tblk, 0, stream>>>(fw2, wt_f2, 4 * DE, DE);

  k_add_emb<<<dim3(2048), blk, 0, stream>>>(x, ns_emb, big0, (long long)N * DE / 4);
  k_f2bf<<<dim3((QNUM * DE + 255) / 256), blk, 0, stream>>>(queries, qs_bf, (long long)QNUM * DE);
  {
    long long pool = (long long)QNUM * DE * 4 + (long long)QNUM * 4 * DE;
    k_zero<<<dim3(1024), blk, 0, stream>>>(q_f, pool);
    k_zero<<<dim3(2048), blk, 0, stream>>>(T_f, (long long)QR * DE);
  }

  // ---- CSR build ----
  k_zero_u32<<<dim3((N + 255) / 256), blk, 0, stream>>>(cnt, N);
  k_count_dst<<<dim3((TOT + 255) / 256), blk, 0, stream>>>(ei, E, TOT, cnt);
  k_scan<<<dim3(1), dim3(1024), 0, stream>>>(cnt, N, rowptr);
  k_zero_u32<<<dim3((N + 255) / 256), blk, 0, stream>>>(cnt, N);
  k_scatter<<<dim3((TOT + 255) / 256), blk, 0, stream>>>(ei, E, TOT, rowptr, cnt, esrc);

  // ---- GAT layers (l0: 256-tile long-K; l1/l2: 128-tile short-K) ----
  k_gemm256<0,0,1><<<dim3(2, MT2), dim3(512), 0, stream>>>(big0, wt_g0, nullptr, hhA,
      8, N, HD, HD, DE, DE, DE, HD, 0, 0, 0, 0);
  k_esed<<<dim3(N), dim3(512), 0, stream>>>(hhA, a_src, a_dst, es, edv);
  k_gat_aggr<2><<<dim3((N + 3) / 4), blk, 0, stream>>>(rowptr, esrc, hhA, es, edv,
      gat_b, hB, N);
  for (int l = 1; l < 3; l++) {
    const bf16* gw = (l == 1) ? wt_g1 : wt_g2;
    k_gemm_nt<0,0,1,0><<<dim3(4, MT1), blk, 0, stream>>>(hB, gw, nullptr, hhA,
        N, HD, HD, HD, HD, HD, 0, 0, 0, 1, HD);
    k_esed<<<dim3(N), dim3(512), 0, stream>>>(hhA, a_src + l * HD, a_dst + l * HD, es, edv);
    if (l < 2)
      k_gat_aggr<2><<<dim3((N + 3) / 4), blk, 0, stream>>>(rowptr, esrc, hhA, es, edv,
          gat_b + l * HD, hB, N);
    else
      k_gat_aggr<0><<<dim3((N + 3) / 4), blk, 0, stream>>>(rowptr, esrc, hhA, es, edv,
          gat_b + l * HD, hB, N);
  }

  // ---- projection -> hD (big0): proj1 128-tile short-K, proj2 256-tile ----
  k_gemm_nt<1,1,1,0><<<dim3(4, MT1), blk, 0, stream>>>(hB, wt_p1, proj_b1, hhA,
      N, HD, HD, HD, HD, HD, 0, 0, 0, 1, HD);
  k_gemm256<0,1,1><<<dim3(10, MT2), dim3(512), 0, stream>>>(hhA, wt_p2, proj_b2, big0,
      8, N, DE, DE, HD, HD, HD, DE, 0, 0, 0, 0);

  // hDT = hD^T [DE][NPAD], pad rows zeroed
  k_transpose_h<<<dim3(NPAD / 32, DE / 32), tblk, 0, stream>>>(big0, hDT, N);

  // ---- q projection (split-K atomic) -> q_bf ----
  k_gemm_nt<0,0,2,0><<<dim3(20, 2, 8), blk, 0, stream>>>(qs_bf, wt_q, nullptr, q_f,
      QNUM, DE, DE, DE, DE, DE, 0, 0, 0, 8, 320);
  k_postproc<0,1,1><<<dim3((QNUM * DE + 255) / 256), blk, 0, stream>>>(q_f, bq, q_bf,
      (long long)QNUM * DE, DE);

  // ---- QK_h = q_h @ Wk_h^T  (batched over heads; bk drops out of softmax) ----
  k_gemm_nt<0,0,1,0><<<dim3(20, 2, 8), blk, 0, stream>>>(q_bf, wkb, nullptr, QK_bf,
      QNUM, DE, ADHD, DE, DE, DE, ADHD, ADHD, (long long)QNUM * DE, 1, ADHD);

  // ---- scores = QK[1600,2560] @ hD^T  (256-tile; B = hD as stored) ----
  k_gemm256<0,0,1><<<dim3((NPAD + 255) / 256, (QR + 255) / 256), dim3(512), 0, stream>>>(
      QK_bf, big0, nullptr, sc, 8, QR, NPAD, N, DE, DE, DE, NPAD, 0, 0, 0, 0);
  k_softmax_row<<<dim3(QR), blk, 0, stream>>>(sc, N);

  // ---- T = attn[1600,NPAD] @ hD  (256-tile, split-K=12, f32 atomic accumulate) ----
  k_gemm256<0,0,2><<<dim3(10, (QR + 255) / 256, 12), dim3(512), 0, stream>>>(
      sc, hDT, nullptr, T_f, 8, QR, DE, DE, NPAD, NPAD, NPAD, DE, 0, 0, 0, 2560);
  k_postproc<0,0,1><<<dim3((QR * DE + 255) / 256), blk, 0, stream>>>(T_f, nullptr, T_bf,
      (long long)QR * DE, DE);

  // ---- ctx_h = T_h @ Wv_h (+bv via rowsum(attn)=1) ----
  k_gemm_nt<0,0,2,0><<<dim3(3, 2, 8 * 8), blk, 0, stream>>>(T_bf, wt_v, nullptr, ctx_f,
      QNUM, ADHD, DE, DE, DE, DE, (long long)QNUM * DE, (long long)ADHD * DE, ADHD, 8, 320);
  k_postproc<0,1,1><<<dim3((QNUM * DE + 255) / 256), blk, 0, stream>>>(ctx_f, bv, ctx_bf,
      (long long)QNUM * DE, DE);

  // ---- output projection + LN1 ----
  k_gemm_nt<0,0,2,0><<<dim3(20, 2, 8), blk, 0, stream>>>(ctx_bf, wt_o, nullptr, attnout,
      QNUM, DE, DE, DE, DE, DE, 0, 0, 0, 8, 320);
  k_postproc<0,1,0><<<dim3((QNUM * DE + 255) / 256), blk, 0, stream>>>(attnout, bo, nullptr,
      (long long)QNUM * DE, DE);
  k_ln<1><<<dim3(QNUM), blk, 0, stream>>>(queries, attnout, ln1g, ln1b, attended, att_bf);

  // ---- FFN + LN2 ----
  k_gemm_nt<0,0,2,0><<<dim3(80, 2, 4), blk, 0, stream>>>(att_bf, wt_f1, nullptr, f1_f,
      QNUM, 4 * DE, DE, DE, DE, 4 * DE, 0, 0, 0, 4, 640);
  k_postproc<1,1,1><<<dim3((QNUM * 4 * DE + 255) / 256), blk, 0, stream>>>(f1_f, fb1, f1_bf,
      (long long)QNUM * 4 * DE, 4 * DE);
  k_gemm_nt<0,0,2,0><<<dim3(20, 2, 8), blk, 0, stream>>>(f1_bf, wt_f2, nullptr, f2_f,
      QNUM, DE, 4 * DE, 4 * DE, 4 * DE, DE, 0, 0, 0, 8, 1280);
  k_postproc<0,1,0><<<dim3((QNUM * DE + 255) / 256), blk, 0, stream>>>(f2_f, fb2, nullptr,
      (long long)QNUM * DE, DE);
  k_ln<0><<<dim3(QNUM), blk, 0, stream>>>(attended, f2_f, ln2g, ln2b, out, nullptr);
}

// Round 13
// 1779.124 us; speedup vs baseline: 1.0514x; 1.0220x over previous
//
#include <hip/hip_runtime.h>
#include <hip/hip_bf16.h>
#include <cmath>

typedef __hip_bfloat16 bf16;
typedef __attribute__((ext_vector_type(8))) short short8;
typedef __attribute__((ext_vector_type(4))) short short4_t;
typedef __attribute__((ext_vector_type(4))) float f32x4;
typedef __attribute__((address_space(1))) void as1_void;
typedef __attribute__((address_space(3))) void as3_void;

#define DE   2560
#define HD   512
#define NPAD 30016
#define QNUM 200
#define ADHD 320
#define QR   1600   // 8 heads * 200 q-rows

static __device__ __forceinline__ float bf2f(bf16 v){ return __bfloat162float(v); }
static __device__ __forceinline__ bf16  f2bf(float v){ return __float2bfloat16(v); }
static __device__ __forceinline__ short bfbits(float f){ bf16 b = f2bf(f); return *reinterpret_cast<short*>(&b); }
static __device__ __forceinline__ float geluf(float x){ return 0.5f*x*(1.0f+erff(x*0.70710678118654752440f)); }
static __device__ __forceinline__ float eluf(float x){ return x>0.f ? x : expm1f(x); }

static __device__ __forceinline__ void gload16(const void* g, void* l){
  __builtin_amdgcn_global_load_lds((as1_void*)g, (as3_void*)l, 16, 0, 0);
}

// =================== 256x256 8-phase bf16 NT GEMM (R4-proven loop) ==========
// C[M,N] = act(A[M,K]*B[N,K]^T + bias). BK=64, 512 thr (8 waves 2Mx4N), 128KB
// LDS dbuf. OBF: 1 = bf16 LDS-retiled store, 0 = f32 direct, 2 = f32 atomicAdd.
template<int ACT, int BIAS, int OBF>
__global__ __launch_bounds__(512, 1)
void k_gemm256(const bf16* __restrict__ A, const bf16* __restrict__ B,
               const float* __restrict__ bias, void* __restrict__ Cv,
               int gm, int M, int N, int NB, int K, int lda, int ldb, int ldc,
               long long sA, long long sB, long long sC, int ks)
{
  __shared__ __align__(16) char smem[131072];   // A:[2][32KB] @0, B:[2][32KB] @64KB
  const int bz = blockIdx.z;
  const bf16* Ab = A + (long long)bz * sA;
  const bf16* Bb = B + (long long)bz * sB;
  const long long cbase = (long long)bz * sC;
  int kbeg = 0, kend = K;
  if (ks > 0) { kbeg = bz * ks; kend = kbeg + ks; if (kend > K) kend = K; }

  // block swizzle: XCD-bijective then gm-supertile over M
  const int gx = gridDim.x, gy = gridDim.y;
  const int nwg = gx * gy;
  int orig = blockIdx.y * gx + blockIdx.x;
  {
    const int q8 = nwg >> 3, r8 = nwg & 7;
    const int xcd = orig & 7, idx = orig >> 3;
    orig = (xcd < r8 ? xcd * (q8 + 1) : r8 * (q8 + 1) + (xcd - r8) * q8) + idx;
  }
  const int per_g = gm * gx;
  const int g = orig / per_g, rem = orig - g * per_g;
  int gsz = gy - g * gm; if (gsz > gm) gsz = gm;
  const int mi = g * gm + rem % gsz;
  const int ni = rem / gsz;
  const int m0 = mi * 256, n0 = ni * 256;

  const int tid = threadIdx.x, lane = tid & 63, wave = tid >> 6;
  const int wm = (wave >> 2) * 128, wn = (wave & 3) * 64;
  const int fr = lane & 15, fg = lane >> 4;
  const int cS0 = ((fg) ^ (fr & 7)) * 16;
  const int cS1 = ((4 + fg) ^ (fr & 7)) * 16;

  const bf16* pA[2][2]; const bf16* pB[2][2];
  #pragma unroll
  for (int L = 0; L < 2; L++) {
    const int ch = L * 512 + tid;
    const int lr = ch >> 3;
    #pragma unroll
    for (int mh = 0; mh < 2; mh++) {
      int r = (lr & 63) + mh * 64 + ((lr & 64) << 1);
      int cs = (ch & 7) ^ (r & 7);
      int gr = m0 + r; if (gr > M - 1) gr = M - 1;
      pA[mh][L] = Ab + (long long)gr * lda + cs * 8;
    }
    #pragma unroll
    for (int nh = 0; nh < 2; nh++) {
      int r = nh * 32 + (lr & 31) + ((lr >> 5) << 6);
      int cs = (ch & 7) ^ (r & 7);
      int gr = n0 + r; if (gr > NB - 1) gr = NB - 1;
      pB[nh][L] = Bb + (long long)gr * ldb + cs * 8;
    }
  }

  #define STG_A(mh, buf, kk) do {                                        \
    char* d_ = smem + (buf) * 32768 + ((mh) * 64 + wave * 8) * 128;      \
    gload16(pA[mh][0] + (kk), d_);                                       \
    gload16(pA[mh][1] + (kk), d_ + 16384);                               \
  } while (0)
  #define STG_B(nh, buf, kk) do {                                        \
    char* d_ = smem + 65536 + (buf) * 32768 +                            \
               ((nh) * 32 + (wave & 3) * 8 + (wave >> 2) * 64) * 128;    \
    gload16(pB[nh][0] + (kk), d_);                                       \
    gload16(pB[nh][1] + (kk), d_ + 16384);                               \
  } while (0)

  f32x4 acc[8][4];
  #pragma unroll
  for (int i = 0; i < 8; i++)
    #pragma unroll
    for (int j = 0; j < 4; j++) acc[i][j] = (f32x4){0.f, 0.f, 0.f, 0.f};

  const int nt = (kend - kbeg) / 64;
  // prologue: tile 0 -> buf 0, granule NEED-order A0,B0,B1,A1
  STG_A(0, 0, kbeg); STG_B(0, 0, kbeg); STG_B(1, 0, kbeg); STG_A(1, 0, kbeg);

  #define LOAD_A(mh) do {                                                \
    _Pragma("unroll")                                                    \
    for (int i = 0; i < 4; i++) {                                        \
      const char* p_ = Ab_l + (wm + (mh) * 64 + i * 16 + fr) * 128;      \
      a_[i][0] = *(const short8*)(p_ + cS0);                             \
      a_[i][1] = *(const short8*)(p_ + cS1);                             \
    }                                                                    \
  } while (0)
  #define LOAD_B(nh) do {                                                \
    _Pragma("unroll")                                                    \
    for (int j = 0; j < 2; j++) {                                        \
      const char* p_ = Bb_l + (wn + (nh) * 32 + j * 16 + fr) * 128;      \
      b_[j][0] = *(const short8*)(p_ + cS0);                             \
      b_[j][1] = *(const short8*)(p_ + cS1);                             \
    }                                                                    \
  } while (0)
  #define MFMA_Q(mh, nh) do {                                            \
    __builtin_amdgcn_s_setprio(1);                                       \
    _Pragma("unroll")                                                    \
    for (int i = 0; i < 4; i++)                                          \
      _Pragma("unroll")                                                  \
      for (int j = 0; j < 2; j++) {                                      \
        acc[(mh)*4+i][(nh)*2+j] = __builtin_amdgcn_mfma_f32_16x16x32_bf16( \
            a_[i][0], b_[j][0], acc[(mh)*4+i][(nh)*2+j], 0, 0, 0);       \
        acc[(mh)*4+i][(nh)*2+j] = __builtin_amdgcn_mfma_f32_16x16x32_bf16( \
            a_[i][1], b_[j][1], acc[(mh)*4+i][(nh)*2+j], 0, 0, 0);       \
      }                                                                  \
    __builtin_amdgcn_s_setprio(0);                                       \
  } while (0)

  for (int t = 0; t < nt; t++) {
    const int buf = t & 1, nb = buf ^ 1;
    const int kn = kbeg + (t + 1) * 64;
    const bool pf = (t + 1 < nt);
    const char* Ab_l = smem + buf * 32768;
    const char* Bb_l = smem + 65536 + buf * 32768;
    short8 a_[4][2], b_[2][2];

    asm volatile("s_waitcnt vmcnt(4)" ::: "memory");
    __builtin_amdgcn_s_barrier();
    LOAD_A(0); LOAD_B(0);
    if (pf) STG_A(0, nb, kn);
    MFMA_Q(0, 0);

    if (pf) { asm volatile("s_waitcnt vmcnt(4)" ::: "memory"); }
    else    { asm volatile("s_waitcnt vmcnt(2)" ::: "memory"); }
    __builtin_amdgcn_s_barrier();
    LOAD_B(1);
    if (pf) STG_B(0, nb, kn);
    MFMA_Q(0, 1);

    if (pf) { asm volatile("s_waitcnt vmcnt(4)" ::: "memory"); }
    else    { asm volatile("s_waitcnt vmcnt(0)" ::: "memory"); }
    __builtin_amdgcn_s_barrier();
    LOAD_A(1);
    if (pf) STG_B(1, nb, kn);
    MFMA_Q(1, 1);

    __builtin_amdgcn_s_barrier();
    LOAD_B(0);
    if (pf) STG_A(1, nb, kn);
    MFMA_Q(1, 0);
  }
  #undef LOAD_A
  #undef LOAD_B
  #undef MFMA_Q
  #undef STG_A
  #undef STG_B

  // ---- epilogue ----
  asm volatile("s_waitcnt vmcnt(0)" ::: "memory");
  __builtin_amdgcn_s_barrier();
  float bv_[4];
  #pragma unroll
  for (int j = 0; j < 4; j++) {
    int c = n0 + wn + j * 16 + fr;
    bv_[j] = (BIAS && c < N) ? bias[c] : 0.f;
  }

  if (OBF == 0 || OBF == 2) {
    float* Cf = (float*)Cv;
    #pragma unroll
    for (int i = 0; i < 8; i++)
      #pragma unroll
      for (int j = 0; j < 4; j++) {
        const int col = n0 + wn + j * 16 + fr;
        if (col >= N) continue;
        #pragma unroll
        for (int r = 0; r < 4; r++) {
          const int row = m0 + wm + i * 16 + fg * 4 + r;
          if (row >= M) continue;
          float v = acc[i][j][r];
          if (BIAS) v += bv_[j];
          if (OBF == 2) atomicAdd(&Cf[cbase + (long long)row * ldc + col], v);
          else          Cf[cbase + (long long)row * ldc + col] = v;
        }
      }
  } else {
    bf16* Cb = (bf16*)Cv;
    bf16* epi = (bf16*)(smem + wave * 16384);   // [128 rows][64 cols]
    #pragma unroll
    for (int i = 0; i < 8; i++)
      #pragma unroll
      for (int j = 0; j < 4; j++)
        #pragma unroll
        for (int r = 0; r < 4; r++) {
          float v = acc[i][j][r];
          if (BIAS) v += bv_[j];
          if (ACT == 1) v = geluf(v);
          else if (ACT == 2) v = eluf(v);
          epi[(i * 16 + fg * 4 + r) * 64 + j * 16 + fr] = f2bf(v);
        }
    #pragma unroll
    for (int it = 0; it < 16; it++) {
      int lrow = it * 8 + (lane >> 3);
      int grow = m0 + wm + lrow;
      int gcol = n0 + wn + (lane & 7) * 8;
      if (grow < M && gcol < N)
        *(short8*)(Cb + cbase + (long long)grow * ldc + gcol) =
            *(const short8*)(epi + lrow * 64 + (lane & 7) * 8);
    }
  }
}

// ---------------- 128-tile NT GEMM (small-M / batched / split-K) ----------------
template<int ACT, int BIAS, int OBF, int TROUT>
__global__ __launch_bounds__(256)
void k_gemm_nt(const bf16* __restrict__ A, const bf16* __restrict__ B,
               const float* __restrict__ bias, void* __restrict__ Cv,
               int M, int N, int K, int lda, int ldb, int ldc,
               long long sA, long long sB, long long sC, int nsplit, int ks)
{
  __shared__ __align__(16) bf16 As[3][128*32];
  __shared__ __align__(16) bf16 Bs[3][128*32];
  const int zb = blockIdx.z;
  const int b  = zb / nsplit;
  const int sl = zb - b*nsplit;
  const int kbeg = sl * ks;
  int kend = kbeg + ks; if (kend > K) kend = K;
  const int nt = (kend > kbeg) ? (kend - kbeg + 31) / 32 : 0;

  const bf16* Ab = A + (long long)b * sA;
  const bf16* Bb = B + (long long)b * sB;
  const long long cbase = (long long)b * sC;

  const int NTt = gridDim.x, MTt = gridDim.y;
  const int nwg = NTt * MTt;
  int orig = blockIdx.y * NTt + blockIdx.x;
  {
    const int q8 = nwg >> 3, r8 = nwg & 7;
    const int xcd = orig & 7, idx = orig >> 3;
    orig = (xcd < r8 ? xcd * (q8 + 1) : r8 * (q8 + 1) + (xcd - r8) * q8) + idx;
  }
  const int GM = 8;
  const int per_g = GM * NTt;
  const int g = orig / per_g, rem = orig - g * per_g;
  int gsz = MTt - g * GM; if (gsz > GM) gsz = GM;
  const int mi = g * GM + rem % gsz;
  const int ni = rem / gsz;

  const int m0 = mi * 128, n0 = ni * 128;
  const int tid = threadIdx.x, lane = tid & 63, wave = tid >> 6;
  const int wm = (wave >> 1) * 64, wn = (wave & 1) * 64;
  const int fr = lane & 15, fg = lane >> 4;
  const int fgs = fg ^ ((fr >> 1) & 3);

  f32x4 acc[4][4];
  #pragma unroll
  for (int i = 0; i < 4; i++)
    #pragma unroll
    for (int j = 0; j < 4; j++) acc[i][j] = (f32x4){0.f, 0.f, 0.f, 0.f};

  const int c0 = wave * 128 + lane;
  const int c1 = c0 + 64;
  const int rA0 = c0 >> 2, rA1 = c1 >> 2;
  const int cc0 = ((c0 & 3) ^ ((rA0 >> 1) & 3)) * 8;
  const int cc1 = ((c1 & 3) ^ ((rA1 >> 1) & 3)) * 8;
  int gra0 = m0 + rA0; if (gra0 >= M) gra0 = M - 1;
  int gra1 = m0 + rA1; if (gra1 >= M) gra1 = M - 1;
  int grb0 = n0 + rA0; if (grb0 >= N) grb0 = N - 1;
  int grb1 = n0 + rA1; if (grb1 >= N) grb1 = N - 1;
  const bf16* pa0 = Ab + (long long)gra0 * lda + cc0;
  const bf16* pa1 = Ab + (long long)gra1 * lda + cc1;
  const bf16* pb0 = Bb + (long long)grb0 * ldb + cc0;
  const bf16* pb1 = Bb + (long long)grb1 * ldb + cc1;

  char* lA = (char*)&As[0][0] + wave * 2048;
  char* lB = (char*)&Bs[0][0] + wave * 2048;

  #define STAGE(buf, kk) do {                       \
    char* a_ = lA + (buf) * 8192;                   \
    char* b_ = lB + (buf) * 8192;                   \
    gload16(pa0 + (kk), a_);                        \
    gload16(pa1 + (kk), a_ + 1024);                 \
    gload16(pb0 + (kk), b_);                        \
    gload16(pb1 + (kk), b_ + 1024);                 \
  } while (0)

  if (nt > 0) STAGE(0, kbeg);
  if (nt > 1) STAGE(1, kbeg + 32);

  int cur = 0;
  for (int t = 0; t < nt; t++) {
    if (t + 2 < nt) {
      int n2 = cur + 2; if (n2 >= 3) n2 -= 3;
      STAGE(n2, kbeg + (t + 2) * 32);
      asm volatile("s_waitcnt vmcnt(8)" ::: "memory");
    } else if (t + 1 < nt) {
      asm volatile("s_waitcnt vmcnt(4)" ::: "memory");
    } else {
      asm volatile("s_waitcnt vmcnt(0)" ::: "memory");
    }
    __builtin_amdgcn_s_barrier();

    const bf16* Asb = (const bf16*)((const char*)&As[0][0] + cur * 8192);
    const bf16* Bsb = (const bf16*)((const char*)&Bs[0][0] + cur * 8192);
    short8 af[4], bfv[4];
    #pragma unroll
    for (int i = 0; i < 4; i++) {
      af[i]  = *(const short8*)(Asb + (wm + i * 16 + fr) * 32 + fgs * 8);
      bfv[i] = *(const short8*)(Bsb + (wn + i * 16 + fr) * 32 + fgs * 8);
    }
    #pragma unroll
    for (int i = 0; i < 4; i++)
      #pragma unroll
      for (int j = 0; j < 4; j++)
        acc[i][j] = __builtin_amdgcn_mfma_f32_16x16x32_bf16(af[i], bfv[j], acc[i][j], 0, 0, 0);

    asm volatile("s_waitcnt lgkmcnt(0)" ::: "memory");
    __builtin_amdgcn_s_barrier();
    cur = cur + 1; if (cur >= 3) cur = 0;
  }
  #undef STAGE

  #pragma unroll
  for (int i = 0; i < 4; i++) {
    const int r0 = m0 + wm + i * 16 + fg * 4;
    #pragma unroll
    for (int j = 0; j < 4; j++) {
      const int col = n0 + wn + j * 16 + fr;
      if (col >= N) continue;
      float bv = 0.f;
      if (BIAS) bv = bias[col];
      #pragma unroll
      for (int r = 0; r < 4; r++) {
        const int row = r0 + r;
        if (row >= M) continue;
        float v = acc[i][j][r] + bv;
        if (ACT == 1) v = geluf(v);
        else if (ACT == 2) v = eluf(v);
        long long off;
        if (TROUT) off = cbase + (long long)col * ldc + row;
        else       off = cbase + (long long)row * ldc + col;
        if (OBF == 1)      ((bf16*)Cv)[off] = f2bf(v);
        else if (OBF == 2) atomicAdd(&((float*)Cv)[off], v);
        else               ((float*)Cv)[off] = v;
      }
    }
  }
}

// ---------------- small utility kernels ----------------
__global__ void k_zero(float* p, long long n) {
  long long i = (long long)blockIdx.x * blockDim.x + threadIdx.x;
  long long st = (long long)gridDim.x * blockDim.x;
  for (; i < n; i += st) p[i] = 0.f;
}

__global__ void k_zero_u32(unsigned* p, int n) {
  int i = blockIdx.x * 256 + threadIdx.x;
  if (i < n) p[i] = 0u;
}

__global__ void k_f2bf(const float* __restrict__ in, bf16* __restrict__ out, long long n) {
  long long i = (long long)blockIdx.x * 256 + threadIdx.x;
  if (i < n) out[i] = f2bf(in[i]);
}

__global__ void k_add_emb(const float* __restrict__ x, const float* __restrict__ ns,
                          bf16* __restrict__ h0, long long n4) {
  long long i = (long long)blockIdx.x * 256 + threadIdx.x;
  long long st = (long long)gridDim.x * 256;
  for (; i < n4; i += st) {
    float4 v = ((const float4*)x)[i];
    int d = (int)(i % (DE / 4)) * 4;
    short4_t o;
    o.x = bfbits(v.x + ns[d]);
    o.y = bfbits(v.y + ns[d + 1]);
    o.z = bfbits(v.z + ns[d + 2]);
    o.w = bfbits(v.w + ns[d + 3]);
    ((short4_t*)h0)[i] = o;
  }
}

// transpose f32 [R,C] -> bf16 [C,R]; R,C multiples of 32
__global__ void k_transpose_bf(const float* __restrict__ W, bf16* __restrict__ Wt, int R, int C) {
  __shared__ float t[32][33];
  int c0 = blockIdx.x * 32, r0 = blockIdx.y * 32;
  int x = threadIdx.x, y = threadIdx.y;
  #pragma unroll
  for (int j = 0; j < 32; j += 8)
    t[y + j][x] = W[(long long)(r0 + y + j) * C + c0 + x];
  __syncthreads();
  #pragma unroll
  for (int j = 0; j < 32; j += 8)
    Wt[(long long)(c0 + y + j) * R + r0 + x] = f2bf(t[x][y + j]);
}

// transpose bf16 src[Nv][DE] -> dst[DE][NPAD], zero-fill rows >= Nv
__global__ void k_transpose_h(const bf16* __restrict__ src, bf16* __restrict__ dst, int Nv) {
  __shared__ bf16 t[32][34];
  int n0 = blockIdx.x * 32, d0 = blockIdx.y * 32;
  int x = threadIdx.x, y = threadIdx.y;
  #pragma unroll
  for (int j = 0; j < 32; j += 8) {
    int n = n0 + y + j;
    t[y + j][x] = (n < Nv) ? src[(long long)n * DE + d0 + x] : f2bf(0.f);
  }
  __syncthreads();
  #pragma unroll
  for (int j = 0; j < 32; j += 8)
    dst[(long long)(d0 + y + j) * NPAD + n0 + x] = t[x][y + j];
}

// ---- CSR build (dst-indexed) ----
__global__ void k_count_dst(const int* __restrict__ ei, int E, int TOT, unsigned* __restrict__ cnt) {
  int e = blockIdx.x * 256 + threadIdx.x;
  if (e >= TOT) return;
  int d = (e < E) ? ei[E + e] : (e - E);
  atomicAdd(&cnt[d], 1u);
}

__global__ __launch_bounds__(1024)
void k_scan(const unsigned* __restrict__ cnt, int n, int* __restrict__ rowptr) {
  __shared__ unsigned tot[1024];
  int t = threadIdx.x;
  int ch = (n + 1023) / 1024;
  int beg = t * ch, end = beg + ch; if (end > n) end = n; if (beg > n) beg = n;
  unsigned s = 0;
  for (int i = beg; i < end; i++) s += cnt[i];
  tot[t] = s;
  __syncthreads();
  for (int o = 1; o < 1024; o <<= 1) {
    unsigned u = (t >= o) ? tot[t - o] : 0u;
    __syncthreads();
    tot[t] += u;
    __syncthreads();
  }
  unsigned run = tot[t] - s;
  for (int i = beg; i < end; i++) { rowptr[i] = (int)run; run += cnt[i]; }
  if (t == 1023) rowptr[n] = (int)tot[1023];
}

__global__ void k_scatter(const int* __restrict__ ei, int E, int TOT,
                          const int* __restrict__ rowptr, unsigned* __restrict__ cursor,
                          int* __restrict__ esrc) {
  int e = blockIdx.x * 256 + threadIdx.x;
  if (e >= TOT) return;
  int s, d;
  if (e < E) { s = ei[e]; d = ei[E + e]; } else { s = d = e - E; }
  unsigned pos = atomicAdd(&cursor[d], 1u);
  esrc[rowptr[d] + pos] = s;
}

// es/ed per node: block = 512 threads, wave w = head
__global__ __launch_bounds__(512)
void k_esed(const bf16* __restrict__ hh, const float* __restrict__ asrc,
            const float* __restrict__ adst, float* __restrict__ es, float* __restrict__ ed) {
  int n = blockIdx.x;
  int h = threadIdx.x >> 6;
  int c = threadIdx.x & 63;
  float v = bf2f(hh[(long long)n * HD + h * 64 + c]);
  float s = v * asrc[h * 64 + c];
  float d = v * adst[h * 64 + c];
  #pragma unroll
  for (int o = 32; o; o >>= 1) { s += __shfl_down(s, o, 64); d += __shfl_down(d, o, 64); }
  if (c == 0) { es[n * 8 + h] = s; ed[n * 8 + h] = d; }
}

// fused GAT aggregation: one wave per destination node; 2-edge unrolled gather.
template<int ACT>
__global__ __launch_bounds__(256)
void k_gat_aggr(const int* __restrict__ rowptr, const int* __restrict__ esrc,
                const bf16* __restrict__ hh, const float* __restrict__ es,
                const float* __restrict__ ed, const float* __restrict__ gb,
                bf16* __restrict__ outp, int Nn)
{
  int w = blockIdx.x * 4 + (threadIdx.x >> 6);
  if (w >= Nn) return;
  int lane = threadIdx.x & 63;
  int h = lane >> 3;
  int beg = rowptr[w], end = rowptr[w + 1];
  float edh = ed[w * 8 + h];
  float mx = -3.0e38f;
  for (int e = beg; e < end; e++) {
    int s = esrc[e];
    float l = es[s * 8 + h] + edh;
    l = l > 0.f ? l : 0.2f * l;
    mx = fmaxf(mx, l);
  }
  float den = 0.f;
  float acc[8] = {0.f, 0.f, 0.f, 0.f, 0.f, 0.f, 0.f, 0.f};
  int e = beg;
  for (; e + 1 < end; e += 2) {
    int s0 = esrc[e], s1 = esrc[e + 1];
    float l0 = es[s0 * 8 + h] + edh; l0 = l0 > 0.f ? l0 : 0.2f * l0;
    float l1 = es[s1 * 8 + h] + edh; l1 = l1 > 0.f ? l1 : 0.2f * l1;
    float ex0 = expf(l0 - mx), ex1 = expf(l1 - mx);
    den += ex0 + ex1;
    short8 v0 = *(const short8*)(hh + (long long)s0 * HD + lane * 8);
    short8 v1 = *(const short8*)(hh + (long long)s1 * HD + lane * 8);
    #pragma unroll
    for (int j = 0; j < 8; j++) {
      short a0 = v0[j], a1 = v1[j];
      acc[j] += ex0 * bf2f(*reinterpret_cast<bf16*>(&a0))
              + ex1 * bf2f(*reinterpret_cast<bf16*>(&a1));
    }
  }
  if (e < end) {
    int s = esrc[e];
    float l = es[s * 8 + h] + edh; l = l > 0.f ? l : 0.2f * l;
    float ex = expf(l - mx);
    den += ex;
    short8 v = *(const short8*)(hh + (long long)s * HD + lane * 8);
    #pragma unroll
    for (int j = 0; j < 8; j++) {
      short a = v[j];
      acc[j] += ex * bf2f(*reinterpret_cast<bf16*>(&a));
    }
  }
  float rs = 1.f / (den + 1e-16f);
  short8 o;
  #pragma unroll
  for (int j = 0; j < 8; j++) {
    float val = acc[j] * rs + gb[lane * 8 + j];
    if (ACT == 2) val = eluf(val);
    o[j] = bfbits(val);
  }
  *(short8*)(outp + (long long)w * HD + lane * 8) = o;
}

template<int ACT, int BIAS, int TOBF>
__global__ void k_postproc(float* __restrict__ acc, const float* __restrict__ bias,
                           bf16* __restrict__ obf, long long tot, int cols) {
  long long i = (long long)blockIdx.x * 256 + threadIdx.x;
  if (i >= tot) return;
  int c = (int)(i % cols);
  float v = acc[i];
  if (BIAS) v += bias[c];
  if (ACT == 1) v = geluf(v);
  if (TOBF) obf[i] = f2bf(v);
  else acc[i] = v;
}

// row softmax (in-place), LDS-cached row: scores bf16 [rows][NPAD], scale folded
__global__ __launch_bounds__(256)
void k_softmax_row(bf16* s_all, int NV) {
  __shared__ __align__(16) bf16 srow[NPAD];   // 60 KB -> 2 blocks/CU
  __shared__ float red[4];
  long long row = blockIdx.x;
  bf16* s = s_all + row * NPAD;
  int tid = threadIdx.x;
  for (int c = tid * 8; c < NV; c += 2048)
    *(short8*)(srow + c) = *(const short8*)(s + c);
  __syncthreads();
  float mx = -3.0e38f;
  for (int c = tid; c < NV; c += 256) mx = fmaxf(mx, bf2f(srow[c]));
  #pragma unroll
  for (int o = 32; o; o >>= 1) mx = fmaxf(mx, __shfl_down(mx, o, 64));
  if ((tid & 63) == 0) red[tid >> 6] = mx;
  __syncthreads();
  mx = fmaxf(fmaxf(red[0], red[1]), fmaxf(red[2], red[3]));
  const float inv = 0.05590169943749474f;  // 1/sqrt(320)
  float sm = 0.f;
  for (int c = tid; c < NV; c += 256) sm += expf((bf2f(srow[c]) - mx) * inv);
  #pragma unroll
  for (int o = 32; o; o >>= 1) sm += __shfl_down(sm, o, 64);
  __syncthreads();
  if ((tid & 63) == 0) red[tid >> 6] = sm;
  __syncthreads();
  sm = red[0] + red[1] + red[2] + red[3];
  float rs = 1.f / sm;
  for (int c = tid * 8; c < NPAD; c += 2048) {
    short8 o;
    #pragma unroll
    for (int j = 0; j < 8; j++) {
      int cc = c + j;
      float v = (cc < NV) ? expf((bf2f(srow[cc]) - mx) * inv) * rs : 0.f;
      o[j] = bfbits(v);
    }
    *(short8*)(s + c) = o;
  }
}

// LayerNorm(a+b) row of DE, optional bf16 dup
template<int WB>
__global__ __launch_bounds__(256)
void k_ln(const float* __restrict__ a, const float* __restrict__ b,
          const float* __restrict__ g, const float* __restrict__ bt,
          float* __restrict__ out, bf16* __restrict__ obf) {
  long long row = blockIdx.x;
  __shared__ float xs[DE];
  __shared__ float red[4];
  int tid = threadIdx.x;
  float sum = 0.f;
  for (int c = tid; c < DE; c += 256) {
    float v = a[row * DE + c] + b[row * DE + c];
    xs[c] = v; sum += v;
  }
  #pragma unroll
  for (int o = 32; o; o >>= 1) sum += __shfl_down(sum, o, 64);
  if ((tid & 63) == 0) red[tid >> 6] = sum;
  __syncthreads();
  float mean = (red[0] + red[1] + red[2] + red[3]) * (1.f / DE);
  float vs = 0.f;
  for (int c = tid; c < DE; c += 256) { float t = xs[c] - mean; vs += t * t; }
  #pragma unroll
  for (int o = 32; o; o >>= 1) vs += __shfl_down(vs, o, 64);
  __syncthreads();
  if ((tid & 63) == 0) red[tid >> 6] = vs;
  __syncthreads();
  float var = (red[0] + red[1] + red[2] + red[3]) * (1.f / DE);
  float sc = rsqrtf(var + 1e-5f);
  for (int c = tid; c < DE; c += 256) {
    float v = (xs[c] - mean) * sc * g[c] + bt[c];
    out[row * DE + c] = v;
    if (WB) obf[row * DE + c] = f2bf(v);
  }
}

// ---------------- host ----------------
extern "C" void kernel_launch(void* const* d_in, const int* in_sizes, int n_in,
                              void* d_out, int out_size, void* d_ws, size_t ws_size,
                              hipStream_t stream)
{
  const float* x       = (const float*)d_in[0];
  const int*   ei      = (const int*)d_in[1];
  const float* ns_emb  = (const float*)d_in[2];
  const float* gat_w0  = (const float*)d_in[3];
  const float* gat_wr  = (const float*)d_in[4];
  const float* a_src   = (const float*)d_in[5];
  const float* a_dst   = (const float*)d_in[6];
  const float* gat_b   = (const float*)d_in[7];
  const float* proj_w1 = (const float*)d_in[8];
  const float* proj_b1 = (const float*)d_in[9];
  const float* proj_w2 = (const float*)d_in[10];
  const float* proj_b2 = (const float*)d_in[11];
  const float* queries = (const float*)d_in[12];
  const float* wq = (const float*)d_in[13]; const float* bq = (const float*)d_in[14];
  const float* wk = (const float*)d_in[15];
  const float* wv = (const float*)d_in[17]; const float* bv = (const float*)d_in[18];
  const float* wo = (const float*)d_in[19]; const float* bo = (const float*)d_in[20];
  const float* ln1g = (const float*)d_in[21]; const float* ln1b = (const float*)d_in[22];
  const float* fw1 = (const float*)d_in[23]; const float* fb1 = (const float*)d_in[24];
  const float* fw2 = (const float*)d_in[25]; const float* fb2 = (const float*)d_in[26];
  const float* ln2g = (const float*)d_in[27]; const float* ln2b = (const float*)d_in[28];
  float* out = (float*)d_out;

  const int N = in_sizes[0] / DE;   // 30000
  const int E = in_sizes[1] / 2;    // 90000
  const int TOT = E + N;            // 120000
  const int MT2 = (N + 255) / 256;  // 118

  char* base = (char*)d_ws;
  size_t off = 0;
  auto AL = [&](size_t bytes) -> void* {
    void* p = base + off;
    off += (bytes + 255) & ~(size_t)255;
    return p;
  };
  bf16* wt_g0 = (bf16*)AL((size_t)HD * DE * 2);
  bf16* wt_g1 = (bf16*)AL((size_t)HD * HD * 2);
  bf16* wt_g2 = (bf16*)AL((size_t)HD * HD * 2);
  bf16* wt_p1 = (bf16*)AL((size_t)HD * HD * 2);
  bf16* wt_p2 = (bf16*)AL((size_t)DE * HD * 2);
  bf16* wt_q  = (bf16*)AL((size_t)DE * DE * 2);
  bf16* wkb   = (bf16*)AL((size_t)DE * DE * 2);   // Wk untransposed, bf16
  bf16* wt_v  = (bf16*)AL((size_t)DE * DE * 2);   // Wv^T
  bf16* wt_o  = (bf16*)AL((size_t)DE * DE * 2);
  bf16* wt_f1 = (bf16*)AL((size_t)4 * DE * DE * 2);
  bf16* wt_f2 = (bf16*)AL((size_t)4 * DE * DE * 2);
  bf16* big0  = (bf16*)AL((size_t)N * DE * 2);      // h0 -> hD
  // bigX carve: QK_bf (8.2MB) + T_f (16.4MB) + T_bf (8.2MB) within 153.6MB
  char* bigX  = (char*)AL((size_t)N * DE * 2);
  bf16*  QK_bf = (bf16*)bigX;
  float* T_f   = (float*)(bigX + (size_t)QR * DE * 2);
  bf16*  T_bf  = (bf16*)((char*)T_f + (size_t)QR * DE * 4);
  bf16* hDT   = (bf16*)AL((size_t)DE * NPAD * 2);   // hD transposed, pad rows zeroed
  // GAT scratch block; union'd with scores buffer `sc` (used after GAT dies)
  const size_t scBytes = (size_t)QR * NPAD * 2;     // 96.05 MB
  size_t gatBytes = 2 * (size_t)N * HD * 2 + 2 * (size_t)N * 8 * 4
                  + (size_t)(N + 1) * 4 + (size_t)TOT * 4 + (size_t)N * 4 + 4096;
  char* gat_blk = (char*)AL(gatBytes > scBytes ? gatBytes : scBytes);
  bf16* hhA = (bf16*)gat_blk;
  bf16* hB  = hhA + (size_t)N * HD;
  float* es  = (float*)(hB + (size_t)N * HD);
  float* edv = es + (size_t)N * 8;
  int* rowptr = (int*)(edv + (size_t)N * 8);
  int* esrc   = rowptr + (N + 1);
  unsigned* cnt = (unsigned*)(esrc + TOT);
  bf16* sc = (bf16*)gat_blk;  // scores/attn [QR][NPAD]
  // small f32 pool (zeroed once; targets of split-K atomic GEMMs)
  float* q_f     = (float*)AL((size_t)QNUM * DE * 4);
  float* ctx_f   = (float*)AL((size_t)QNUM * DE * 4);
  float* attnout = (float*)AL((size_t)QNUM * DE * 4);
  float* f1_f    = (float*)AL((size_t)QNUM * 4 * DE * 4);
  float* f2_f    = (float*)AL((size_t)QNUM * DE * 4);
  bf16* qs_bf  = (bf16*)AL((size_t)QNUM * DE * 2);
  bf16* q_bf   = (bf16*)AL((size_t)QNUM * DE * 2);
  bf16* ctx_bf = (bf16*)AL((size_t)QNUM * DE * 2);
  float* attended = (float*)AL((size_t)QNUM * DE * 4);
  bf16* att_bf = (bf16*)AL((size_t)QNUM * DE * 2);
  bf16* f1_bf  = (bf16*)AL((size_t)QNUM * 4 * DE * 2);

  dim3 blk(256);
  dim3 tblk(32, 8);

  // weight prep
  k_transpose_bf<<<dim3(HD / 32, DE / 32), tblk, 0, stream>>>(gat_w0, wt_g0, DE, HD);
  k_transpose_bf<<<dim3(HD / 32, HD / 32), tblk, 0, stream>>>(gat_wr, wt_g1, HD, HD);
  k_transpose_bf<<<dim3(HD / 32, HD / 32), tblk, 0, stream>>>(gat_wr + (size_t)HD * HD, wt_g2, HD, HD);
  k_transpose_bf<<<dim3(HD / 32, HD / 32), tblk, 0, stream>>>(proj_w1, wt_p1, HD, HD);
  k_transpose_bf<<<dim3(DE / 32, HD / 32), tblk, 0, stream>>>(proj_w2, wt_p2, HD, DE);
  k_transpose_bf<<<dim3(DE / 32, DE / 32), tblk, 0, stream>>>(wq, wt_q, DE, DE);
  k_f2bf<<<dim3((DE * DE + 255) / 256), blk, 0, stream>>>(wk, wkb, (long long)DE * DE);
  k_transpose_bf<<<dim3(DE / 32, DE / 32), tblk, 0, stream>>>(wv, wt_v, DE, DE);
  k_transpose_bf<<<dim3(DE / 32, DE / 32), tblk, 0, stream>>>(wo, wt_o, DE, DE);
  k_transpose_bf<<<dim3(4 * DE / 32, DE / 32), tblk, 0, stream>>>(fw1, wt_f1, DE, 4 * DE);
  k_transpose_bf<<<dim3(DE / 32, 4 * DE / 32), tblk, 0, stream>>>(fw2, wt_f2, 4 * DE, DE);

  k_add_emb<<<dim3(2048), blk, 0, stream>>>(x, ns_emb, big0, (long long)N * DE / 4);
  k_f2bf<<<dim3((QNUM * DE + 255) / 256), blk, 0, stream>>>(queries, qs_bf, (long long)QNUM * DE);
  {
    long long pool = (long long)QNUM * DE * 4 + (long long)QNUM * 4 * DE;
    k_zero<<<dim3(1024), blk, 0, stream>>>(q_f, pool);
    k_zero<<<dim3(2048), blk, 0, stream>>>(T_f, (long long)QR * DE);
  }

  // ---- CSR build ----
  k_zero_u32<<<dim3((N + 255) / 256), blk, 0, stream>>>(cnt, N);
  k_count_dst<<<dim3((TOT + 255) / 256), blk, 0, stream>>>(ei, E, TOT, cnt);
  k_scan<<<dim3(1), dim3(1024), 0, stream>>>(cnt, N, rowptr);
  k_zero_u32<<<dim3((N + 255) / 256), blk, 0, stream>>>(cnt, N);
  k_scatter<<<dim3((TOT + 255) / 256), blk, 0, stream>>>(ei, E, TOT, rowptr, cnt, esrc);

  // ---- GAT layers (all 256-tile; R10-proven geometry) ----
  const bf16* gw[3] = { wt_g0, wt_g1, wt_g2 };
  for (int l = 0; l < 3; l++) {
    const bf16* Ain = (l == 0) ? big0 : hB;
    int Kd = (l == 0) ? DE : HD;
    k_gemm256<0,0,1><<<dim3(2, MT2), dim3(512), 0, stream>>>(Ain, gw[l], nullptr, hhA,
        8, N, HD, HD, Kd, Kd, Kd, HD, 0, 0, 0, 0);
    k_esed<<<dim3(N), dim3(512), 0, stream>>>(hhA, a_src + l * HD, a_dst + l * HD, es, edv);
    if (l < 2)
      k_gat_aggr<2><<<dim3((N + 3) / 4), blk, 0, stream>>>(rowptr, esrc, hhA, es, edv,
          gat_b + l * HD, hB, N);
    else
      k_gat_aggr<0><<<dim3((N + 3) / 4), blk, 0, stream>>>(rowptr, esrc, hhA, es, edv,
          gat_b + l * HD, hB, N);
  }

  // ---- projection -> hD (big0) ----
  k_gemm256<1,1,1><<<dim3(2, MT2), dim3(512), 0, stream>>>(hB, wt_p1, proj_b1, hhA,
      8, N, HD, HD, HD, HD, HD, HD, 0, 0, 0, 0);
  k_gemm256<0,1,1><<<dim3(10, MT2), dim3(512), 0, stream>>>(hhA, wt_p2, proj_b2, big0,
      8, N, DE, DE, HD, HD, HD, DE, 0, 0, 0, 0);

  // hDT = hD^T [DE][NPAD], pad rows zeroed
  k_transpose_h<<<dim3(NPAD / 32, DE / 32), tblk, 0, stream>>>(big0, hDT, N);

  // ---- q projection (split-K atomic) -> q_bf ----
  k_gemm_nt<0,0,2,0><<<dim3(20, 2, 8), blk, 0, stream>>>(qs_bf, wt_q, nullptr, q_f,
      QNUM, DE, DE, DE, DE, DE, 0, 0, 0, 8, 320);
  k_postproc<0,1,1><<<dim3((QNUM * DE + 255) / 256), blk, 0, stream>>>(q_f, bq, q_bf,
      (long long)QNUM * DE, DE);

  // ---- QK_h = q_h @ Wk_h^T  (batched over heads; bk drops out of softmax) ----
  k_gemm_nt<0,0,1,0><<<dim3(20, 2, 8), blk, 0, stream>>>(q_bf, wkb, nullptr, QK_bf,
      QNUM, DE, ADHD, DE, DE, DE, ADHD, ADHD, (long long)QNUM * DE, 1, ADHD);

  // ---- scores = QK[1600,2560] @ hD^T  (256-tile; B = hD as stored) ----
  k_gemm256<0,0,1><<<dim3((NPAD + 255) / 256, (QR + 255) / 256), dim3(512), 0, stream>>>(
      QK_bf, big0, nullptr, sc, 8, QR, NPAD, N, DE, DE, DE, NPAD, 0, 0, 0, 0);
  k_softmax_row<<<dim3(QR), blk, 0, stream>>>(sc, N);

  // ---- T = attn[1600,NPAD] @ hD  (256-tile, split-K=12, f32 atomic accumulate) ----
  k_gemm256<0,0,2><<<dim3(10, (QR + 255) / 256, 12), dim3(512), 0, stream>>>(
      sc, hDT, nullptr, T_f, 8, QR, DE, DE, NPAD, NPAD, NPAD, DE, 0, 0, 0, 2560);
  k_postproc<0,0,1><<<dim3((QR * DE + 255) / 256), blk, 0, stream>>>(T_f, nullptr, T_bf,
      (long long)QR * DE, DE);

  // ---- ctx_h = T_h @ Wv_h (+bv via rowsum(attn)=1) ----
  k_gemm_nt<0,0,2,0><<<dim3(3, 2, 8 * 8), blk, 0, stream>>>(T_bf, wt_v, nullptr, ctx_f,
      QNUM, ADHD, DE, DE, DE, DE, (long long)QNUM * DE, (long long)ADHD * DE, ADHD, 8, 320);
  k_postproc<0,1,1><<<dim3((QNUM * DE + 255) / 256), blk, 0, stream>>>(ctx_f, bv, ctx_bf,
      (long long)QNUM * DE, DE);

  // ---- output projection + LN1 ----
  k_gemm_nt<0,0,2,0><<<dim3(20, 2, 8), blk, 0, stream>>>(ctx_bf, wt_o, nullptr, attnout,
      QNUM, DE, DE, DE, DE, DE, 0, 0, 0, 8, 320);
  k_postproc<0,1,0><<<dim3((QNUM * DE + 255) / 256), blk, 0, stream>>>(attnout, bo, nullptr,
      (long long)QNUM * DE, DE);
  k_ln<1><<<dim3(QNUM), blk, 0, stream>>>(queries, attnout, ln1g, ln1b, attended, att_bf);

  // ---- FFN + LN2 ----
  k_gemm_nt<0,0,2,0><<<dim3(80, 2, 4), blk, 0, stream>>>(att_bf, wt_f1, nullptr, f1_f,
      QNUM, 4 * DE, DE, DE, DE, 4 * DE, 0, 0, 0, 4, 640);
  k_postproc<1,1,1><<<dim3((QNUM * 4 * DE + 255) / 256), blk, 0, stream>>>(f1_f, fb1, f1_bf,
      (long long)QNUM * 4 * DE, 4 * DE);
  k_gemm_nt<0,0,2,0><<<dim3(20, 2, 8), blk, 0, stream>>>(f1_bf, wt_f2, nullptr, f2_f,
      QNUM, DE, 4 * DE, 4 * DE, 4 * DE, DE, 0, 0, 0, 8, 1280);
  k_postproc<0,1,0><<<dim3((QNUM * DE + 255) / 256), blk, 0, stream>>>(f2_f, fb2, nullptr,
      (long long)QNUM * DE, DE);
  k_ln<0><<<dim3(QNUM), blk, 0, stream>>>(attended, f2_f, ln2g, ln2b, out, nullptr);
}